// Round 7
// baseline (387.582 us; speedup 1.0000x reference)
//
#include <hip/hip_runtime.h>
#include <stdint.h>

#define D_FEAT 128
#define D_OUT  64
#define BSH 7              // 128 nodes per bucket
#define MAXB 1024          // max buckets (N <= 131072)
#define APITCH 136         // agg_s row pitch in ushorts (272 B, 16B-aligned, 2-way banks)

typedef __attribute__((ext_vector_type(8))) short short8;   // 8 bf16 (4 VGPRs)
typedef __attribute__((ext_vector_type(8))) ushort ushort8; // 8 bf16
typedef __attribute__((ext_vector_type(4))) float f32x4;
typedef __attribute__((ext_vector_type(2))) float f32x2;

// ---------------------------------------------------------------------------
// helpers
// ---------------------------------------------------------------------------
__device__ __forceinline__ ushort f2bf(float f) {            // RNE f32->bf16
  uint32_t u = __float_as_uint(f);
  return (ushort)((u + 0x7FFFu + ((u >> 16) & 1u)) >> 16);
}
__device__ __forceinline__ f32x2 bf2f2(uint32_t v) {         // 2 bf16 -> 2 f32
  f32x2 r;
  r.x = __uint_as_float(v << 16);
  r.y = __uint_as_float(v & 0xFFFF0000u);
  return r;
}

__device__ __forceinline__ void threefry2x32(uint32_t k0, uint32_t k1,
                                             uint32_t& x0, uint32_t& x1) {
  uint32_t k2 = k0 ^ k1 ^ 0x1BD11BDAu;
#define TF_ROT(r) { x0 += x1; x1 = (x1 << (r)) | (x1 >> (32 - (r))); x1 ^= x0; }
  x0 += k0; x1 += k1;
  TF_ROT(13) TF_ROT(15) TF_ROT(26) TF_ROT(6)
  x0 += k1; x1 += k2 + 1u;
  TF_ROT(17) TF_ROT(29) TF_ROT(16) TF_ROT(24)
  x0 += k2; x1 += k0 + 2u;
  TF_ROT(13) TF_ROT(15) TF_ROT(26) TF_ROT(6)
  x0 += k0; x1 += k1 + 3u;
  TF_ROT(17) TF_ROT(29) TF_ROT(16) TF_ROT(24)
  x0 += k1; x1 += k2 + 4u;
  TF_ROT(13) TF_ROT(15) TF_ROT(26) TF_ROT(6)
  x0 += k2; x1 += k0 + 5u;
#undef TF_ROT
}

// keep iff top bit of (r0^r1) of threefry2x32((0,42), (0, i)) is 0
__device__ __forceinline__ bool keep_bit(uint32_t i) {
  uint32_t t0 = 0u, t1 = i;
  threefry2x32(0u, 42u, t0, t1);
  return (((t0 ^ t1) >> 31) == 0u);
}

// ---------------------------------------------------------------------------
// edge_index dtype detection: int64 rows => all odd u32 words are zero
// ---------------------------------------------------------------------------
__global__ void detect_kernel(const uint32_t* __restrict__ ei, int* __restrict__ flag) {
  uint32_t v = ei[2 * threadIdx.x + 1];
  unsigned long long nz = __ballot(v != 0u);
  if (threadIdx.x == 0) flag[0] = (nz == 0ull) ? 1 : 0;
}

__device__ __forceinline__ int load_dst(const void* ei, int is64, long E, long e) {
  return is64 ? (int)((const long long*)ei)[E + e] : ((const int*)ei)[E + e];
}
__device__ __forceinline__ int load_src(const void* ei, int is64, long E, long e) {
  return is64 ? (int)((const long long*)ei)[e] : ((const int*)ei)[e];
}

// ---------------------------------------------------------------------------
// input conversions / weight packing
// ---------------------------------------------------------------------------
__global__ __launch_bounds__(256) void convx_kernel(
    const float4* __restrict__ x, ushort* __restrict__ xb, long n4) {
  long i = (long)blockIdx.x * blockDim.x + threadIdx.x;
  if (i >= n4) return;
  float4 v = x[i];
  ushort4 o = {f2bf(v.x), f2bf(v.y), f2bf(v.z), f2bf(v.w)};
  *(ushort4*)(xb + i * 4) = o;
}

// w1t[j][k] = bf16(k<128 ? W1l[k][j] : W1r[k-128][j]),  j<128, k<256
__global__ __launch_bounds__(256) void packw1_kernel(
    const float* __restrict__ Wl, const float* __restrict__ Wr,
    ushort* __restrict__ wt) {
  int idx = blockIdx.x * blockDim.x + threadIdx.x;   // 128*256
  if (idx >= 128 * 256) return;
  int j = idx >> 8, k = idx & 255;
  float v = (k < 128) ? Wl[k * 128 + j] : Wr[(k - 128) * 128 + j];
  wt[j * 256 + k] = f2bf(v);
}

// w2t[j][k] = bf16(k<128 ? W2l[k][j] : W2r[k-128][j]),  j<64, k<256
__global__ __launch_bounds__(256) void packw2_kernel(
    const float* __restrict__ Wl, const float* __restrict__ Wr,
    ushort* __restrict__ wt) {
  int idx = blockIdx.x * blockDim.x + threadIdx.x;   // 64*256
  if (idx >= 64 * 256) return;
  int j = idx >> 8, k = idx & 255;
  float v = (k < 128) ? Wl[k * 64 + j] : Wr[(k - 128) * 64 + j];
  wt[j * 256 + k] = f2bf(v);
}

// ---------------------------------------------------------------------------
// CSR build via bucketed counting sort (no random 4B scatter)
// ---------------------------------------------------------------------------
__global__ __launch_bounds__(256) void bucket_hist(
    const void* __restrict__ ei, const int* __restrict__ flag,
    int* __restrict__ bucketCnt, long E, int chunk, int nbuck) {
  __shared__ int cnt[MAXB];
  const int is64 = flag[0];
  long beg = (long)blockIdx.x * chunk;
  long end = beg + chunk; if (end > E) end = E;
  for (int i = threadIdx.x; i < nbuck; i += 256) cnt[i] = 0;
  __syncthreads();
  for (long e = beg + threadIdx.x; e < end; e += 256)
    atomicAdd(&cnt[load_dst(ei, is64, E, e) >> BSH], 1);
  __syncthreads();
  for (int i = threadIdx.x; i < nbuck; i += 256)
    if (cnt[i]) atomicAdd(&bucketCnt[i], cnt[i]);
}

// scan buckets (single block, 1024 threads); also seeds cursors & rowptr[N]
__global__ __launch_bounds__(1024) void bucket_scan(
    const int* __restrict__ bucketCnt, int* __restrict__ bucketPtr,
    int* __restrict__ bucketCur, int* __restrict__ rowptr,
    int N, int nbuck, int E) {
  __shared__ int ts[1024];
  int tid = threadIdx.x;
  int v = (tid < nbuck) ? bucketCnt[tid] : 0;
  ts[tid] = v;
  __syncthreads();
  for (int off = 1; off < 1024; off <<= 1) {
    int t = (tid >= off) ? ts[tid - off] : 0;
    __syncthreads();
    ts[tid] += t;
    __syncthreads();
  }
  if (tid < nbuck) {
    int excl = ts[tid] - v;
    bucketPtr[tid] = excl;
    bucketCur[tid] = excl;
  }
  if (tid == 0) { bucketPtr[nbuck] = E; rowptr[N] = E; }
}

// S2: scatter packed (src<<BSH | dst&mask) into bucket regions
__global__ __launch_bounds__(256) void bucket_scatter(
    const void* __restrict__ ei, const int* __restrict__ flag,
    int* __restrict__ bucketCur, uint32_t* __restrict__ packed,
    long E, int chunk, int nbuck) {
  __shared__ int cnt[MAXB];
  __shared__ int base[MAXB];
  __shared__ int cur[MAXB];
  const int is64 = flag[0];
  long beg = (long)blockIdx.x * chunk;
  long end = beg + chunk; if (end > E) end = E;
  for (int i = threadIdx.x; i < nbuck; i += 256) { cnt[i] = 0; cur[i] = 0; }
  __syncthreads();
  for (long e = beg + threadIdx.x; e < end; e += 256)
    atomicAdd(&cnt[load_dst(ei, is64, E, e) >> BSH], 1);
  __syncthreads();
  for (int i = threadIdx.x; i < nbuck; i += 256)
    base[i] = cnt[i] ? atomicAdd(&bucketCur[i], cnt[i]) : 0;
  __syncthreads();
  for (long e = beg + threadIdx.x; e < end; e += 256) {
    int dst = load_dst(ei, is64, E, e);
    int src = load_src(ei, is64, E, e);
    int b = dst >> BSH;
    int off = atomicAdd(&cur[b], 1);
    packed[base[b] + off] = ((uint32_t)src << BSH) | (uint32_t)(dst & ((1 << BSH) - 1));
  }
}

// S3: per bucket -> local hist + scan -> rowptr, invd, contiguous col writes
__global__ __launch_bounds__(256) void bucket_build(
    const uint32_t* __restrict__ packed, const int* __restrict__ bucketPtr,
    int* __restrict__ col, int* __restrict__ rowptr, float* __restrict__ invd,
    int N, int nbuck) {
  __shared__ int lcnt[1 << BSH];
  __shared__ int lbase[1 << BSH];
  __shared__ int lcur[1 << BSH];
  const int b = blockIdx.x;
  const int tid = threadIdx.x;
  const int beg = bucketPtr[b], end = bucketPtr[b + 1];
  if (tid < 128) { lcnt[tid] = 0; lcur[tid] = 0; }
  __syncthreads();
  for (int i = beg + tid; i < end; i += 256)
    atomicAdd(&lcnt[packed[i] & 127], 1);
  __syncthreads();
  if (tid < 128) lbase[tid] = lcnt[tid];
  __syncthreads();
  for (int off = 1; off < 128; off <<= 1) {
    int t = (tid >= off && tid < 128) ? lbase[tid - off] : 0;
    __syncthreads();
    if (tid < 128) lbase[tid] += t;
    __syncthreads();
  }
  if (tid < 128) {
    int excl = lbase[tid] - lcnt[tid];
    lbase[tid] = excl;
    int n = (b << BSH) + tid;
    if (n < N) {
      rowptr[n] = beg + excl;
      int d = lcnt[tid];
      invd[n] = 1.0f / (float)(d > 1 ? d : 1);
    }
  }
  __syncthreads();
  for (int i = beg + tid; i < end; i += 256) {
    uint32_t p = packed[i];
    int l = p & 127;
    int pos = beg + lbase[l] + atomicAdd(&lcur[l], 1);
    col[pos] = (int)(p >> BSH);
  }
}

// ---------------------------------------------------------------------------
// gather phase (device func): mean-aggregate 16 nodes per wave into LDS
// 16 B/lane, quarter-wave per source row, 8 edges/iter, 32-bit voffsets
// ---------------------------------------------------------------------------
__device__ __forceinline__ void gather_to_lds(
    const ushort* __restrict__ featb, const int* __restrict__ rowptr,
    const int* __restrict__ col, const float* __restrict__ invd,
    ushort (*agg_s)[APITCH], int node_base, int wv, int lane, int N) {
  const int q = lane >> 4;
  const int sl = lane & 15;
  const uint32_t slb = (uint32_t)sl * 16u;       // byte offset within row
  const char* xc = (const char*)featb;

  for (int t = 0; t < 16; ++t) {
    int ln = wv * 16 + t;
    int n = node_base + ln;
    if (n < N) {
      int beg = rowptr[n], end = rowptr[n + 1];
      f32x2 acc[4];
#pragma unroll
      for (int i = 0; i < 4; i++) acc[i] = (f32x2){0.f, 0.f};
      for (int e = beg; e < end; e += 8) {
        int i0 = e + q, i1 = i0 + 4;
        bool v0 = i0 < end, v1 = i1 < end;
        uint32_t o0 = ((uint32_t)col[v0 ? i0 : beg] << 8) + slb;
        uint32_t o1 = ((uint32_t)col[v1 ? i1 : beg] << 8) + slb;
        uint4 a = *(const uint4*)(xc + o0);
        uint4 b = *(const uint4*)(xc + o1);
        if (v0) {
          acc[0] += bf2f2(a.x); acc[1] += bf2f2(a.y);
          acc[2] += bf2f2(a.z); acc[3] += bf2f2(a.w);
        }
        if (v1) {
          acc[0] += bf2f2(b.x); acc[1] += bf2f2(b.y);
          acc[2] += bf2f2(b.z); acc[3] += bf2f2(b.w);
        }
      }
#pragma unroll
      for (int i = 0; i < 4; i++) {
        acc[i].x += __shfl_xor(acc[i].x, 16);
        acc[i].y += __shfl_xor(acc[i].y, 16);
        acc[i].x += __shfl_xor(acc[i].x, 32);
        acc[i].y += __shfl_xor(acc[i].y, 32);
      }
      if (q == 0) {
        float sc = invd[n];
        ushort8 o;
#pragma unroll
        for (int i = 0; i < 4; i++) {
          o[2 * i]     = f2bf(acc[i].x * sc);
          o[2 * i + 1] = f2bf(acc[i].y * sc);
        }
        *(ushort8*)&agg_s[ln][sl * 8] = o;
      }
    } else if (q == 0) {
      *(ushort8*)&agg_s[ln][sl * 8] = (ushort8){0, 0, 0, 0, 0, 0, 0, 0};
    }
  }
}

// ---------------------------------------------------------------------------
// fused layer 1: gather(x)->LDS, then h1d = bf16(dropout(relu([agg|x]@W1+b1)))
// block = 256 = 4 waves, 64 nodes; wave computes 16 nodes x 128 cols
// ---------------------------------------------------------------------------
__global__ __launch_bounds__(256) void fused1_kernel(
    const ushort* __restrict__ xb, const int* __restrict__ rowptr,
    const int* __restrict__ col, const float* __restrict__ invd,
    const ushort* __restrict__ w1t, const float* __restrict__ b1,
    ushort* __restrict__ h1d, int N) {
  __shared__ ushort agg_s[64][APITCH];
  __shared__ unsigned long long mask_s[64][2];
  const int lane = threadIdx.x & 63;
  const int wv = threadIdx.x >> 6;
  const int node_base = blockIdx.x * 64;

  // dropout masks for this wave's 16 nodes (2 threefry + 2 ballots per node)
  for (int t = 0; t < 16; ++t) {
    int ln = wv * 16 + t;
    int n = node_base + ln;
    if (n < N) {
      uint32_t mb = (uint32_t)n * 128u;
      unsigned long long w0 = __ballot(keep_bit(mb + (uint32_t)lane));
      unsigned long long w1 = __ballot(keep_bit(mb + 64u + (uint32_t)lane));
      if (lane == 0) { mask_s[ln][0] = w0; mask_s[ln][1] = w1; }
    } else if (lane == 0) {
      mask_s[ln][0] = 0ull; mask_s[ln][1] = 0ull;
    }
  }

  gather_to_lds(xb, rowptr, col, invd, agg_s, node_base, wv, lane, N);
  __syncthreads();

  // GEMM phase
  const int r16 = lane & 15;
  const int kg = lane >> 4;
  int arow = node_base + wv * 16 + r16;
  int grow = (arow >= N) ? (N - 1) : arow;

  f32x4 acc[8];
#pragma unroll
  for (int i = 0; i < 8; i++) acc[i] = (f32x4){0.f, 0.f, 0.f, 0.f};

  const ushort* als = &agg_s[wv * 16 + r16][kg * 8];
  const ushort* a1 = xb + (long)grow * 128 + kg * 8;
  const ushort* wb = w1t + r16 * 256 + kg * 8;

#pragma unroll
  for (int s = 0; s < 8; s++) {
    short8 a = (s < 4) ? *(const short8*)(als + s * 32)
                       : *(const short8*)(a1 + (s - 4) * 32);
#pragma unroll
    for (int ct = 0; ct < 8; ct++) {
      short8 b = *(const short8*)(wb + ct * (16 * 256) + s * 32);
      acc[ct] = __builtin_amdgcn_mfma_f32_16x16x32_bf16(a, b, acc[ct], 0, 0, 0);
    }
  }

  float bbv[8];
#pragma unroll
  for (int ct = 0; ct < 8; ct++) bbv[ct] = b1[ct * 16 + r16];

#pragma unroll
  for (int r = 0; r < 4; r++) {
    int ln = wv * 16 + kg * 4 + r;
    int n = node_base + ln;
    if (n < N) {
      unsigned long long m0 = mask_s[ln][0];
      unsigned long long m1 = mask_s[ln][1];
#pragma unroll
      for (int ct = 0; ct < 8; ct++) {
        int j = ct * 16 + r16;
        float h = fmaxf(acc[ct][r] + bbv[ct], 0.f);
        unsigned long long w = (j & 64) ? m1 : m0;
        bool keep = (w >> (j & 63)) & 1ull;
        h1d[(long)n * 128 + j] = keep ? f2bf(2.0f * h) : (ushort)0;
      }
    }
  }
}

// ---------------------------------------------------------------------------
// fused layer 2: gather(h1)->LDS, then out = logsm([agg2|h1]@W2 + b2)
// ---------------------------------------------------------------------------
__global__ __launch_bounds__(256) void fused2_kernel(
    const ushort* __restrict__ h1d, const int* __restrict__ rowptr,
    const int* __restrict__ col, const float* __restrict__ invd,
    const ushort* __restrict__ w2t, const float* __restrict__ b2,
    float* __restrict__ out, int N) {
  __shared__ ushort agg_s[64][APITCH];
  const int lane = threadIdx.x & 63;
  const int wv = threadIdx.x >> 6;
  const int node_base = blockIdx.x * 64;

  gather_to_lds(h1d, rowptr, col, invd, agg_s, node_base, wv, lane, N);
  __syncthreads();

  const int r16 = lane & 15;
  const int kg = lane >> 4;
  int arow = node_base + wv * 16 + r16;
  int grow = (arow >= N) ? (N - 1) : arow;

  f32x4 acc[4];
#pragma unroll
  for (int i = 0; i < 4; i++) acc[i] = (f32x4){0.f, 0.f, 0.f, 0.f};

  const ushort* als = &agg_s[wv * 16 + r16][kg * 8];
  const ushort* a1 = h1d + (long)grow * 128 + kg * 8;
  const ushort* wb = w2t + r16 * 256 + kg * 8;

#pragma unroll
  for (int s = 0; s < 8; s++) {
    short8 a = (s < 4) ? *(const short8*)(als + s * 32)
                       : *(const short8*)(a1 + (s - 4) * 32);
#pragma unroll
    for (int ct = 0; ct < 4; ct++) {
      short8 b = *(const short8*)(wb + ct * (16 * 256) + s * 32);
      acc[ct] = __builtin_amdgcn_mfma_f32_16x16x32_bf16(a, b, acc[ct], 0, 0, 0);
    }
  }

  float bb[4];
#pragma unroll
  for (int ct = 0; ct < 4; ct++) bb[ct] = b2[ct * 16 + r16];

#pragma unroll
  for (int r = 0; r < 4; r++) {
    float v[4];
#pragma unroll
    for (int ct = 0; ct < 4; ct++) v[ct] = acc[ct][r] + bb[ct];
    float m = fmaxf(fmaxf(v[0], v[1]), fmaxf(v[2], v[3]));
#pragma unroll
    for (int off = 1; off < 16; off <<= 1) m = fmaxf(m, __shfl_xor(m, off));
    float s = expf(v[0] - m) + expf(v[1] - m) + expf(v[2] - m) + expf(v[3] - m);
#pragma unroll
    for (int off = 1; off < 16; off <<= 1) s += __shfl_xor(s, off);
    float ls = logf(s);
    int n = node_base + wv * 16 + kg * 4 + r;
    if (n < N) {
#pragma unroll
      for (int ct = 0; ct < 4; ct++)
        out[(long)n * 64 + ct * 16 + r16] = v[ct] - m - ls;
    }
  }
}

// ---------------------------------------------------------------------------
extern "C" void kernel_launch(void* const* d_in, const int* in_sizes, int n_in,
                              void* d_out, int out_size, void* d_ws, size_t ws_size,
                              hipStream_t stream) {
  const float* x   = (const float*)d_in[0];
  const void*  ei  = d_in[1];
  const float* W1l = (const float*)d_in[2];
  const float* b1  = (const float*)d_in[3];
  const float* W1r = (const float*)d_in[4];
  const float* W2l = (const float*)d_in[5];
  const float* b2  = (const float*)d_in[6];
  const float* W2r = (const float*)d_in[7];
  float* out = (float*)d_out;

  const int  N  = in_sizes[0] / D_FEAT;    // 100000
  const long E  = (long)in_sizes[1] / 2;   // 1600000
  const long NF = (long)N * D_FEAT;        // 12.8M
  const int  nbuck = (N + (1 << BSH) - 1) >> BSH;   // 782

  char* ws = (char*)d_ws;
  size_t off = 0;
  auto alloc = [&](size_t bytes) -> void* {
    void* p = ws + off;
    off = (off + bytes + 255) & ~(size_t)255;
    return p;
  };
  int*      bucketCnt = (int*)alloc(sizeof(int) * MAXB);
  int*      bucketPtr = (int*)alloc(sizeof(int) * (MAXB + 1));
  int*      bucketCur = (int*)alloc(sizeof(int) * MAXB);
  int*      rowptr    = (int*)alloc(sizeof(int) * (N + 1));
  int*      col       = (int*)alloc(sizeof(int) * E);
  uint32_t* packed    = (uint32_t*)alloc(sizeof(uint32_t) * E);
  float*    invd      = (float*)alloc(sizeof(float) * N);
  ushort*   xb        = (ushort*)alloc(sizeof(ushort) * NF);
  ushort*   h1d       = (ushort*)alloc(sizeof(ushort) * NF);
  ushort*   w1t       = (ushort*)alloc(sizeof(ushort) * 128 * 256);
  ushort*   w2t       = (ushort*)alloc(sizeof(ushort) * 64 * 256);
  int*      flag      = (int*)alloc(sizeof(int));

  const int chunkE = (int)((E + 255) / 256);   // edges per block, 256 blocks

  hipMemsetAsync(bucketCnt, 0, sizeof(int) * MAXB, stream);

  detect_kernel<<<1, 64, 0, stream>>>((const uint32_t*)ei, flag);
  convx_kernel<<<(int)((NF / 4 + 255) / 256), 256, 0, stream>>>((const float4*)x, xb, NF / 4);
  packw1_kernel<<<128, 256, 0, stream>>>(W1l, W1r, w1t);
  packw2_kernel<<<64, 256, 0, stream>>>(W2l, W2r, w2t);

  bucket_hist<<<256, 256, 0, stream>>>(ei, flag, bucketCnt, E, chunkE, nbuck);
  bucket_scan<<<1, 1024, 0, stream>>>(bucketCnt, bucketPtr, bucketCur, rowptr, N, nbuck, (int)E);
  bucket_scatter<<<256, 256, 0, stream>>>(ei, flag, bucketCur, packed, E, chunkE, nbuck);
  bucket_build<<<nbuck, 256, 0, stream>>>(packed, bucketPtr, col, rowptr, invd, N, nbuck);

  const int gemmBlocks = (N + 63) / 64;    // 1563

  fused1_kernel<<<gemmBlocks, 256, 0, stream>>>(xb, rowptr, col, invd, w1t, b1, h1d, N);
  fused2_kernel<<<gemmBlocks, 256, 0, stream>>>(h1d, rowptr, col, invd, w2t, b2, out, N);
}

// Round 8
// 297.012 us; speedup vs baseline: 1.3049x; 1.3049x over previous
//
#include <hip/hip_runtime.h>
#include <stdint.h>

#define D_FEAT 128
#define D_OUT  64
#define BSH 7              // 128 nodes per bucket
#define MAXB 1024          // max buckets (N <= 131072)

typedef __attribute__((ext_vector_type(8))) short short8;   // 8 bf16 (4 VGPRs)
typedef __attribute__((ext_vector_type(8))) ushort ushort8; // 8 bf16
typedef __attribute__((ext_vector_type(4))) float f32x4;
typedef __attribute__((ext_vector_type(2))) float f32x2;

// ---------------------------------------------------------------------------
// helpers
// ---------------------------------------------------------------------------
__device__ __forceinline__ ushort f2bf(float f) {            // RNE f32->bf16
  uint32_t u = __float_as_uint(f);
  return (ushort)((u + 0x7FFFu + ((u >> 16) & 1u)) >> 16);
}
__device__ __forceinline__ f32x2 bf2f2(uint32_t v) {         // 2 bf16 -> 2 f32
  f32x2 r;
  r.x = __uint_as_float(v << 16);
  r.y = __uint_as_float(v & 0xFFFF0000u);
  return r;
}

__device__ __forceinline__ void threefry2x32(uint32_t k0, uint32_t k1,
                                             uint32_t& x0, uint32_t& x1) {
  uint32_t k2 = k0 ^ k1 ^ 0x1BD11BDAu;
#define TF_ROT(r) { x0 += x1; x1 = (x1 << (r)) | (x1 >> (32 - (r))); x1 ^= x0; }
  x0 += k0; x1 += k1;
  TF_ROT(13) TF_ROT(15) TF_ROT(26) TF_ROT(6)
  x0 += k1; x1 += k2 + 1u;
  TF_ROT(17) TF_ROT(29) TF_ROT(16) TF_ROT(24)
  x0 += k2; x1 += k0 + 2u;
  TF_ROT(13) TF_ROT(15) TF_ROT(26) TF_ROT(6)
  x0 += k0; x1 += k1 + 3u;
  TF_ROT(17) TF_ROT(29) TF_ROT(16) TF_ROT(24)
  x0 += k1; x1 += k2 + 4u;
  TF_ROT(13) TF_ROT(15) TF_ROT(26) TF_ROT(6)
  x0 += k2; x1 += k0 + 5u;
#undef TF_ROT
}

// keep iff top bit of (r0^r1) of threefry2x32((0,42), (0, i)) is 0
__device__ __forceinline__ bool keep_bit(uint32_t i) {
  uint32_t t0 = 0u, t1 = i;
  threefry2x32(0u, 42u, t0, t1);
  return (((t0 ^ t1) >> 31) == 0u);
}

// ---------------------------------------------------------------------------
// edge_index dtype detection: int64 rows => all odd u32 words are zero
// ---------------------------------------------------------------------------
__global__ void detect_kernel(const uint32_t* __restrict__ ei, int* __restrict__ flag) {
  uint32_t v = ei[2 * threadIdx.x + 1];
  unsigned long long nz = __ballot(v != 0u);
  if (threadIdx.x == 0) flag[0] = (nz == 0ull) ? 1 : 0;
}

__device__ __forceinline__ int load_dst(const void* ei, int is64, long E, long e) {
  return is64 ? (int)((const long long*)ei)[E + e] : ((const int*)ei)[E + e];
}
__device__ __forceinline__ int load_src(const void* ei, int is64, long E, long e) {
  return is64 ? (int)((const long long*)ei)[e] : ((const int*)ei)[e];
}

// ---------------------------------------------------------------------------
// input conversions / weight packing
// ---------------------------------------------------------------------------
__global__ __launch_bounds__(256) void convx_kernel(
    const float4* __restrict__ x, ushort* __restrict__ xb, long n4) {
  long i = (long)blockIdx.x * blockDim.x + threadIdx.x;
  if (i >= n4) return;
  float4 v = x[i];
  ushort4 o = {f2bf(v.x), f2bf(v.y), f2bf(v.z), f2bf(v.w)};
  *(ushort4*)(xb + i * 4) = o;
}

// w1t[j][k] = bf16(k<128 ? W1l[k][j] : W1r[k-128][j]),  j<128, k<256
__global__ __launch_bounds__(256) void packw1_kernel(
    const float* __restrict__ Wl, const float* __restrict__ Wr,
    ushort* __restrict__ wt) {
  int idx = blockIdx.x * blockDim.x + threadIdx.x;   // 128*256
  if (idx >= 128 * 256) return;
  int j = idx >> 8, k = idx & 255;
  float v = (k < 128) ? Wl[k * 128 + j] : Wr[(k - 128) * 128 + j];
  wt[j * 256 + k] = f2bf(v);
}

// w2t[j][k] = bf16(k<128 ? W2l[k][j] : W2r[k-128][j]),  j<64, k<256
__global__ __launch_bounds__(256) void packw2_kernel(
    const float* __restrict__ Wl, const float* __restrict__ Wr,
    ushort* __restrict__ wt) {
  int idx = blockIdx.x * blockDim.x + threadIdx.x;   // 64*256
  if (idx >= 64 * 256) return;
  int j = idx >> 8, k = idx & 255;
  float v = (k < 128) ? Wl[k * 64 + j] : Wr[(k - 128) * 64 + j];
  wt[j * 256 + k] = f2bf(v);
}

// ---------------------------------------------------------------------------
// CSR build via bucketed counting sort (no random 4B scatter)
// ---------------------------------------------------------------------------
__global__ __launch_bounds__(256) void bucket_hist(
    const void* __restrict__ ei, const int* __restrict__ flag,
    int* __restrict__ bucketCnt, long E, int chunk, int nbuck) {
  __shared__ int cnt[MAXB];
  const int is64 = flag[0];
  long beg = (long)blockIdx.x * chunk;
  long end = beg + chunk; if (end > E) end = E;
  for (int i = threadIdx.x; i < nbuck; i += 256) cnt[i] = 0;
  __syncthreads();
  for (long e = beg + threadIdx.x; e < end; e += 256)
    atomicAdd(&cnt[load_dst(ei, is64, E, e) >> BSH], 1);
  __syncthreads();
  for (int i = threadIdx.x; i < nbuck; i += 256)
    if (cnt[i]) atomicAdd(&bucketCnt[i], cnt[i]);
}

// scan buckets (single block, 1024 threads); also seeds cursors & rowptr[N]
__global__ __launch_bounds__(1024) void bucket_scan(
    const int* __restrict__ bucketCnt, int* __restrict__ bucketPtr,
    int* __restrict__ bucketCur, int* __restrict__ rowptr,
    int N, int nbuck, int E) {
  __shared__ int ts[1024];
  int tid = threadIdx.x;
  int v = (tid < nbuck) ? bucketCnt[tid] : 0;
  ts[tid] = v;
  __syncthreads();
  for (int off = 1; off < 1024; off <<= 1) {
    int t = (tid >= off) ? ts[tid - off] : 0;
    __syncthreads();
    ts[tid] += t;
    __syncthreads();
  }
  if (tid < nbuck) {
    int excl = ts[tid] - v;
    bucketPtr[tid] = excl;
    bucketCur[tid] = excl;
  }
  if (tid == 0) { bucketPtr[nbuck] = E; rowptr[N] = E; }
}

// S2: scatter packed (src<<BSH | dst&mask) into bucket regions
__global__ __launch_bounds__(256) void bucket_scatter(
    const void* __restrict__ ei, const int* __restrict__ flag,
    int* __restrict__ bucketCur, uint32_t* __restrict__ packed,
    long E, int chunk, int nbuck) {
  __shared__ int cnt[MAXB];
  __shared__ int base[MAXB];
  __shared__ int cur[MAXB];
  const int is64 = flag[0];
  long beg = (long)blockIdx.x * chunk;
  long end = beg + chunk; if (end > E) end = E;
  for (int i = threadIdx.x; i < nbuck; i += 256) { cnt[i] = 0; cur[i] = 0; }
  __syncthreads();
  for (long e = beg + threadIdx.x; e < end; e += 256)
    atomicAdd(&cnt[load_dst(ei, is64, E, e) >> BSH], 1);
  __syncthreads();
  for (int i = threadIdx.x; i < nbuck; i += 256)
    base[i] = cnt[i] ? atomicAdd(&bucketCur[i], cnt[i]) : 0;
  __syncthreads();
  for (long e = beg + threadIdx.x; e < end; e += 256) {
    int dst = load_dst(ei, is64, E, e);
    int src = load_src(ei, is64, E, e);
    int b = dst >> BSH;
    int off = atomicAdd(&cur[b], 1);
    packed[base[b] + off] = ((uint32_t)src << BSH) | (uint32_t)(dst & ((1 << BSH) - 1));
  }
}

// S3: per bucket -> local hist + scan -> rowptr, invd, contiguous col writes
__global__ __launch_bounds__(256) void bucket_build(
    const uint32_t* __restrict__ packed, const int* __restrict__ bucketPtr,
    int* __restrict__ col, int* __restrict__ rowptr, float* __restrict__ invd,
    int N, int nbuck) {
  __shared__ int lcnt[1 << BSH];
  __shared__ int lbase[1 << BSH];
  __shared__ int lcur[1 << BSH];
  const int b = blockIdx.x;
  const int tid = threadIdx.x;
  const int beg = bucketPtr[b], end = bucketPtr[b + 1];
  if (tid < 128) { lcnt[tid] = 0; lcur[tid] = 0; }
  __syncthreads();
  for (int i = beg + tid; i < end; i += 256)
    atomicAdd(&lcnt[packed[i] & 127], 1);
  __syncthreads();
  if (tid < 128) lbase[tid] = lcnt[tid];
  __syncthreads();
  for (int off = 1; off < 128; off <<= 1) {
    int t = (tid >= off && tid < 128) ? lbase[tid - off] : 0;
    __syncthreads();
    if (tid < 128) lbase[tid] += t;
    __syncthreads();
  }
  if (tid < 128) {
    int excl = lbase[tid] - lcnt[tid];
    lbase[tid] = excl;
    int n = (b << BSH) + tid;
    if (n < N) {
      rowptr[n] = beg + excl;
      int d = lcnt[tid];
      invd[n] = 1.0f / (float)(d > 1 ? d : 1);
    }
  }
  __syncthreads();
  for (int i = beg + tid; i < end; i += 256) {
    uint32_t p = packed[i];
    int l = p & 127;
    int pos = beg + lbase[l] + atomicAdd(&lcur[l], 1);
    col[pos] = (int)(p >> BSH);
  }
}

// ---------------------------------------------------------------------------
// gather-style mean aggregation (bf16 in, fp32 pk accum, bf16 out)
// one wave per node; 16 B/lane -> quarter-wave per source row
// main loop: 16 edges/iter unpredicated; tail: <=15 edges predicated
// optionally generates the packed dropout mask (2 threefry + 2 ballots/wave)
// ---------------------------------------------------------------------------
__global__ __launch_bounds__(256) void agg_kernel(
    const ushort* __restrict__ featb, const int* __restrict__ rowptr,
    const int* __restrict__ col, const float* __restrict__ invd,
    ushort* __restrict__ aggb, unsigned long long* __restrict__ maskb, int N) {
  const int lane = threadIdx.x & 63;
  const int q  = lane >> 4;            // quarter 0..3
  const int sl = lane & 15;            // 16 B slice of the 256 B row
  const uint32_t slb = (uint32_t)sl * 16u;
  int n = (int)(((long)blockIdx.x * blockDim.x + threadIdx.x) >> 6);
  if (n >= N) return;

  if (maskb) {  // dropout mask for node n, packed 128 bits -> 2 x u64
    uint32_t base = (uint32_t)n * 128u;
    bool k0 = keep_bit(base + (uint32_t)lane);
    bool k1 = keep_bit(base + 64u + (uint32_t)lane);
    unsigned long long w0 = __ballot(k0);
    unsigned long long w1 = __ballot(k1);
    if (lane == 0) {
      maskb[2 * n]     = w0;
      maskb[2 * n + 1] = w1;
    }
  }

  const char* xc = (const char*)featb;
  const int beg = rowptr[n], end = rowptr[n + 1];

  f32x2 acc[4];
#pragma unroll
  for (int i = 0; i < 4; i++) acc[i] = (f32x2){0.f, 0.f};

  int e = beg;
  const int fend = beg + ((end - beg) & ~15);   // full 16-edge groups

  for (; e < fend; e += 16) {
    uint32_t o0 = ((uint32_t)col[e + q]      << 8) + slb;
    uint32_t o1 = ((uint32_t)col[e + 4 + q]  << 8) + slb;
    uint32_t o2 = ((uint32_t)col[e + 8 + q]  << 8) + slb;
    uint32_t o3 = ((uint32_t)col[e + 12 + q] << 8) + slb;
    uint4 a = *(const uint4*)(xc + o0);
    uint4 b = *(const uint4*)(xc + o1);
    uint4 c = *(const uint4*)(xc + o2);
    uint4 d = *(const uint4*)(xc + o3);
    acc[0] += bf2f2(a.x); acc[1] += bf2f2(a.y); acc[2] += bf2f2(a.z); acc[3] += bf2f2(a.w);
    acc[0] += bf2f2(b.x); acc[1] += bf2f2(b.y); acc[2] += bf2f2(b.z); acc[3] += bf2f2(b.w);
    acc[0] += bf2f2(c.x); acc[1] += bf2f2(c.y); acc[2] += bf2f2(c.z); acc[3] += bf2f2(c.w);
    acc[0] += bf2f2(d.x); acc[1] += bf2f2(d.y); acc[2] += bf2f2(d.z); acc[3] += bf2f2(d.w);
  }

  for (; e < end; e += 8) {            // tail: at most 2 iterations
    int i0 = e + q, i1 = i0 + 4;
    bool v0 = i0 < end, v1 = i1 < end;
    uint32_t o0 = ((uint32_t)col[v0 ? i0 : beg] << 8) + slb;
    uint32_t o1 = ((uint32_t)col[v1 ? i1 : beg] << 8) + slb;
    uint4 a = *(const uint4*)(xc + o0);
    uint4 b = *(const uint4*)(xc + o1);
    if (v0) {
      acc[0] += bf2f2(a.x); acc[1] += bf2f2(a.y);
      acc[2] += bf2f2(a.z); acc[3] += bf2f2(a.w);
    }
    if (v1) {
      acc[0] += bf2f2(b.x); acc[1] += bf2f2(b.y);
      acc[2] += bf2f2(b.z); acc[3] += bf2f2(b.w);
    }
  }

  // combine the 4 quarter-wave partial sums (lanes with equal sl)
#pragma unroll
  for (int i = 0; i < 4; i++) {
    acc[i].x += __shfl_xor(acc[i].x, 16);
    acc[i].y += __shfl_xor(acc[i].y, 16);
    acc[i].x += __shfl_xor(acc[i].x, 32);
    acc[i].y += __shfl_xor(acc[i].y, 32);
  }

  if (q == 0) {
    float sc = invd[n];
    ushort8 o;
#pragma unroll
    for (int i = 0; i < 4; i++) {
      o[2 * i]     = f2bf(acc[i].x * sc);
      o[2 * i + 1] = f2bf(acc[i].y * sc);
    }
    *(ushort8*)(aggb + (long)n * D_FEAT + sl * 8) = o;
  }
}

// ---------------------------------------------------------------------------
// layer 1 (MFMA): h1d = bf16(dropout(relu([agg|x]@[W1l;W1r] + b1)))
// block = 256 = 4 waves; wave computes 16 nodes x 128 cols
// dropout mask read from packed bits (no threefry here)
// ---------------------------------------------------------------------------
__global__ __launch_bounds__(256) void layer1_kernel(
    const ushort* __restrict__ aggb, const ushort* __restrict__ xb,
    const ushort* __restrict__ w1t, const float* __restrict__ b1,
    const unsigned long long* __restrict__ maskb,
    ushort* __restrict__ h1d, int N) {
  const int lane = threadIdx.x & 63;
  const int wv = threadIdx.x >> 6;
  const int node_base = blockIdx.x * 64 + wv * 16;
  const int r16 = lane & 15;
  const int kg = lane >> 4;
  int arow = node_base + r16;
  if (arow >= N) arow = N - 1;

  f32x4 acc[8];
#pragma unroll
  for (int i = 0; i < 8; i++) acc[i] = (f32x4){0.f, 0.f, 0.f, 0.f};

  const ushort* a0 = aggb + (long)arow * 128 + kg * 8;
  const ushort* a1 = xb + (long)arow * 128 + kg * 8;
  const ushort* wb = w1t + r16 * 256 + kg * 8;

#pragma unroll
  for (int s = 0; s < 8; s++) {
    short8 a = (s < 4) ? *(const short8*)(a0 + s * 32)
                       : *(const short8*)(a1 + (s - 4) * 32);
#pragma unroll
    for (int ct = 0; ct < 8; ct++) {
      short8 b = *(const short8*)(wb + ct * (16 * 256) + s * 32);
      acc[ct] = __builtin_amdgcn_mfma_f32_16x16x32_bf16(a, b, acc[ct], 0, 0, 0);
    }
  }

  float bbv[8];
#pragma unroll
  for (int ct = 0; ct < 8; ct++) bbv[ct] = b1[ct * 16 + r16];

#pragma unroll
  for (int r = 0; r < 4; r++) {
    int n = node_base + kg * 4 + r;
    if (n < N) {
      unsigned long long m0 = maskb[2 * n];
      unsigned long long m1 = maskb[2 * n + 1];
#pragma unroll
      for (int ct = 0; ct < 8; ct++) {
        int j = ct * 16 + r16;
        float h = fmaxf(acc[ct][r] + bbv[ct], 0.f);
        unsigned long long w = (j & 64) ? m1 : m0;
        bool keep = (w >> (j & 63)) & 1ull;
        h1d[(long)n * 128 + j] = keep ? f2bf(2.0f * h) : (ushort)0;
      }
    }
  }
}

// ---------------------------------------------------------------------------
// layer 2 (MFMA) + log_softmax: out = logsm([agg2|h1]@[W2l;W2r] + b2)
// ---------------------------------------------------------------------------
__global__ __launch_bounds__(256) void layer2_kernel(
    const ushort* __restrict__ aggb, const ushort* __restrict__ h1d,
    const ushort* __restrict__ w2t, const float* __restrict__ b2,
    float* __restrict__ out, int N) {
  const int lane = threadIdx.x & 63;
  const int wv = threadIdx.x >> 6;
  const int node_base = blockIdx.x * 64 + wv * 16;
  const int r16 = lane & 15;
  const int kg = lane >> 4;
  int arow = node_base + r16;
  if (arow >= N) arow = N - 1;

  f32x4 acc[4];
#pragma unroll
  for (int i = 0; i < 4; i++) acc[i] = (f32x4){0.f, 0.f, 0.f, 0.f};

  const ushort* a0 = aggb + (long)arow * 128 + kg * 8;
  const ushort* a1 = h1d + (long)arow * 128 + kg * 8;
  const ushort* wb = w2t + r16 * 256 + kg * 8;

#pragma unroll
  for (int s = 0; s < 8; s++) {
    short8 a = (s < 4) ? *(const short8*)(a0 + s * 32)
                       : *(const short8*)(a1 + (s - 4) * 32);
#pragma unroll
    for (int ct = 0; ct < 4; ct++) {
      short8 b = *(const short8*)(wb + ct * (16 * 256) + s * 32);
      acc[ct] = __builtin_amdgcn_mfma_f32_16x16x32_bf16(a, b, acc[ct], 0, 0, 0);
    }
  }

  float bb[4];
#pragma unroll
  for (int ct = 0; ct < 4; ct++) bb[ct] = b2[ct * 16 + r16];

#pragma unroll
  for (int r = 0; r < 4; r++) {
    float v[4];
#pragma unroll
    for (int ct = 0; ct < 4; ct++) v[ct] = acc[ct][r] + bb[ct];
    float m = fmaxf(fmaxf(v[0], v[1]), fmaxf(v[2], v[3]));
#pragma unroll
    for (int off = 1; off < 16; off <<= 1) m = fmaxf(m, __shfl_xor(m, off));
    float s = expf(v[0] - m) + expf(v[1] - m) + expf(v[2] - m) + expf(v[3] - m);
#pragma unroll
    for (int off = 1; off < 16; off <<= 1) s += __shfl_xor(s, off);
    float ls = logf(s);
    int n = node_base + kg * 4 + r;
    if (n < N) {
#pragma unroll
      for (int ct = 0; ct < 4; ct++)
        out[(long)n * 64 + ct * 16 + r16] = v[ct] - m - ls;
    }
  }
}

// ---------------------------------------------------------------------------
extern "C" void kernel_launch(void* const* d_in, const int* in_sizes, int n_in,
                              void* d_out, int out_size, void* d_ws, size_t ws_size,
                              hipStream_t stream) {
  const float* x   = (const float*)d_in[0];
  const void*  ei  = d_in[1];
  const float* W1l = (const float*)d_in[2];
  const float* b1  = (const float*)d_in[3];
  const float* W1r = (const float*)d_in[4];
  const float* W2l = (const float*)d_in[5];
  const float* b2  = (const float*)d_in[6];
  const float* W2r = (const float*)d_in[7];
  float* out = (float*)d_out;

  const int  N  = in_sizes[0] / D_FEAT;    // 100000
  const long E  = (long)in_sizes[1] / 2;   // 1600000
  const long NF = (long)N * D_FEAT;        // 12.8M
  const int  nbuck = (N + (1 << BSH) - 1) >> BSH;   // 782

  char* ws = (char*)d_ws;
  size_t off = 0;
  auto alloc = [&](size_t bytes) -> void* {
    void* p = ws + off;
    off = (off + bytes + 255) & ~(size_t)255;
    return p;
  };
  int*      bucketCnt = (int*)alloc(sizeof(int) * MAXB);
  int*      bucketPtr = (int*)alloc(sizeof(int) * (MAXB + 1));
  int*      bucketCur = (int*)alloc(sizeof(int) * MAXB);
  int*      rowptr    = (int*)alloc(sizeof(int) * (N + 1));
  int*      col       = (int*)alloc(sizeof(int) * E);
  uint32_t* packed    = (uint32_t*)alloc(sizeof(uint32_t) * E);
  float*    invd      = (float*)alloc(sizeof(float) * N);
  ushort*   xb        = (ushort*)alloc(sizeof(ushort) * NF);
  ushort*   aggb      = (ushort*)alloc(sizeof(ushort) * NF);
  ushort*   h1d       = (ushort*)alloc(sizeof(ushort) * NF);
  ushort*   w1t       = (ushort*)alloc(sizeof(ushort) * 128 * 256);
  ushort*   w2t       = (ushort*)alloc(sizeof(ushort) * 64 * 256);
  unsigned long long* maskb = (unsigned long long*)alloc(sizeof(unsigned long long) * 2 * N);
  int*      flag      = (int*)alloc(sizeof(int));

  const int chunkE = (int)((E + 255) / 256);   // edges per block, 256 blocks

  hipMemsetAsync(bucketCnt, 0, sizeof(int) * MAXB, stream);

  detect_kernel<<<1, 64, 0, stream>>>((const uint32_t*)ei, flag);
  convx_kernel<<<(int)((NF / 4 + 255) / 256), 256, 0, stream>>>((const float4*)x, xb, NF / 4);
  packw1_kernel<<<128, 256, 0, stream>>>(W1l, W1r, w1t);
  packw2_kernel<<<64, 256, 0, stream>>>(W2l, W2r, w2t);

  bucket_hist<<<256, 256, 0, stream>>>(ei, flag, bucketCnt, E, chunkE, nbuck);
  bucket_scan<<<1, 1024, 0, stream>>>(bucketCnt, bucketPtr, bucketCur, rowptr, N, nbuck, (int)E);
  bucket_scatter<<<256, 256, 0, stream>>>(ei, flag, bucketCur, packed, E, chunkE, nbuck);
  bucket_build<<<nbuck, 256, 0, stream>>>(packed, bucketPtr, col, rowptr, invd, N, nbuck);

  const int aggBlocks = (int)(((long)N * 64 + 255) / 256);
  const int gemmBlocks = (N + 63) / 64;

  agg_kernel<<<aggBlocks, 256, 0, stream>>>(xb, rowptr, col, invd, aggb, maskb, N);
  layer1_kernel<<<gemmBlocks, 256, 0, stream>>>(aggb, xb, w1t, b1, maskb, h1d, N);

  agg_kernel<<<aggBlocks, 256, 0, stream>>>(h1d, rowptr, col, invd, aggb, nullptr, N);
  layer2_kernel<<<gemmBlocks, 256, 0, stream>>>(aggb, h1d, w2t, b2, out, N);
}

// Round 9
// 241.833 us; speedup vs baseline: 1.6027x; 1.2282x over previous
//
#include <hip/hip_runtime.h>
#include <stdint.h>

#define D_FEAT 128
#define D_OUT  64
#define BSH 7              // 128 nodes per bucket
#define MAXB 1024          // max buckets (N <= 131072)

typedef __attribute__((ext_vector_type(8))) short short8;   // 8 bf16 (4 VGPRs)
typedef __attribute__((ext_vector_type(8))) ushort ushort8; // 8 bf16
typedef __attribute__((ext_vector_type(4))) float f32x4;
typedef __attribute__((ext_vector_type(2))) float f32x2;

// ---------------------------------------------------------------------------
// helpers
// ---------------------------------------------------------------------------
__device__ __forceinline__ ushort f2bf(float f) {            // RNE f32->bf16
  uint32_t u = __float_as_uint(f);
  return (ushort)((u + 0x7FFFu + ((u >> 16) & 1u)) >> 16);
}
__device__ __forceinline__ f32x2 bf2f2(uint32_t v) {         // 2 bf16 -> 2 f32
  f32x2 r;
  r.x = __uint_as_float(v << 16);
  r.y = __uint_as_float(v & 0xFFFF0000u);
  return r;
}

__device__ __forceinline__ void threefry2x32(uint32_t k0, uint32_t k1,
                                             uint32_t& x0, uint32_t& x1) {
  uint32_t k2 = k0 ^ k1 ^ 0x1BD11BDAu;
#define TF_ROT(r) { x0 += x1; x1 = (x1 << (r)) | (x1 >> (32 - (r))); x1 ^= x0; }
  x0 += k0; x1 += k1;
  TF_ROT(13) TF_ROT(15) TF_ROT(26) TF_ROT(6)
  x0 += k1; x1 += k2 + 1u;
  TF_ROT(17) TF_ROT(29) TF_ROT(16) TF_ROT(24)
  x0 += k2; x1 += k0 + 2u;
  TF_ROT(13) TF_ROT(15) TF_ROT(26) TF_ROT(6)
  x0 += k0; x1 += k1 + 3u;
  TF_ROT(17) TF_ROT(29) TF_ROT(16) TF_ROT(24)
  x0 += k1; x1 += k2 + 4u;
  TF_ROT(13) TF_ROT(15) TF_ROT(26) TF_ROT(6)
  x0 += k2; x1 += k0 + 5u;
#undef TF_ROT
}

// keep iff top bit of (r0^r1) of threefry2x32((0,42), (0, i)) is 0
__device__ __forceinline__ bool keep_bit(uint32_t i) {
  uint32_t t0 = 0u, t1 = i;
  threefry2x32(0u, 42u, t0, t1);
  return (((t0 ^ t1) >> 31) == 0u);
}

// ---------------------------------------------------------------------------
// edge_index dtype detection: int64 rows => all odd u32 words are zero
// ---------------------------------------------------------------------------
__global__ void detect_kernel(const uint32_t* __restrict__ ei, int* __restrict__ flag) {
  uint32_t v = ei[2 * threadIdx.x + 1];
  unsigned long long nz = __ballot(v != 0u);
  if (threadIdx.x == 0) flag[0] = (nz == 0ull) ? 1 : 0;
}

__device__ __forceinline__ int load_dst(const void* ei, int is64, long E, long e) {
  return is64 ? (int)((const long long*)ei)[E + e] : ((const int*)ei)[E + e];
}
__device__ __forceinline__ int load_src(const void* ei, int is64, long E, long e) {
  return is64 ? (int)((const long long*)ei)[e] : ((const int*)ei)[e];
}

// ---------------------------------------------------------------------------
// input conversions / weight packing
// ---------------------------------------------------------------------------
__global__ __launch_bounds__(256) void convx_kernel(
    const float4* __restrict__ x, ushort* __restrict__ xb, long n4) {
  long i = (long)blockIdx.x * blockDim.x + threadIdx.x;
  if (i >= n4) return;
  float4 v = x[i];
  ushort4 o = {f2bf(v.x), f2bf(v.y), f2bf(v.z), f2bf(v.w)};
  *(ushort4*)(xb + i * 4) = o;
}

// w1t[j][k] = bf16(k<128 ? W1l[k][j] : W1r[k-128][j]),  j<128, k<256
__global__ __launch_bounds__(256) void packw1_kernel(
    const float* __restrict__ Wl, const float* __restrict__ Wr,
    ushort* __restrict__ wt) {
  int idx = blockIdx.x * blockDim.x + threadIdx.x;   // 128*256
  if (idx >= 128 * 256) return;
  int j = idx >> 8, k = idx & 255;
  float v = (k < 128) ? Wl[k * 128 + j] : Wr[(k - 128) * 128 + j];
  wt[j * 256 + k] = f2bf(v);
}

// w2t[j][k] = bf16(k<128 ? W2l[k][j] : W2r[k-128][j]),  j<64, k<256
__global__ __launch_bounds__(256) void packw2_kernel(
    const float* __restrict__ Wl, const float* __restrict__ Wr,
    ushort* __restrict__ wt) {
  int idx = blockIdx.x * blockDim.x + threadIdx.x;   // 64*256
  if (idx >= 64 * 256) return;
  int j = idx >> 8, k = idx & 255;
  float v = (k < 128) ? Wl[k * 64 + j] : Wr[(k - 128) * 64 + j];
  wt[j * 256 + k] = f2bf(v);
}

// ---------------------------------------------------------------------------
// CSR build via bucketed counting sort (no random 4B scatter)
// ---------------------------------------------------------------------------
__global__ __launch_bounds__(256) void bucket_hist(
    const void* __restrict__ ei, const int* __restrict__ flag,
    int* __restrict__ bucketCnt, long E, int chunk, int nbuck) {
  __shared__ int cnt[MAXB];
  const int is64 = flag[0];
  long beg = (long)blockIdx.x * chunk;
  long end = beg + chunk; if (end > E) end = E;
  for (int i = threadIdx.x; i < nbuck; i += 256) cnt[i] = 0;
  __syncthreads();
  for (long e = beg + threadIdx.x; e < end; e += 256)
    atomicAdd(&cnt[load_dst(ei, is64, E, e) >> BSH], 1);
  __syncthreads();
  for (int i = threadIdx.x; i < nbuck; i += 256)
    if (cnt[i]) atomicAdd(&bucketCnt[i], cnt[i]);
}

// scan buckets (single block, 1024 threads); also seeds cursors & rowptr[N]
__global__ __launch_bounds__(1024) void bucket_scan(
    const int* __restrict__ bucketCnt, int* __restrict__ bucketPtr,
    int* __restrict__ bucketCur, int* __restrict__ rowptr,
    int N, int nbuck, int E) {
  __shared__ int ts[1024];
  int tid = threadIdx.x;
  int v = (tid < nbuck) ? bucketCnt[tid] : 0;
  ts[tid] = v;
  __syncthreads();
  for (int off = 1; off < 1024; off <<= 1) {
    int t = (tid >= off) ? ts[tid - off] : 0;
    __syncthreads();
    ts[tid] += t;
    __syncthreads();
  }
  if (tid < nbuck) {
    int excl = ts[tid] - v;
    bucketPtr[tid] = excl;
    bucketCur[tid] = excl;
  }
  if (tid == 0) { bucketPtr[nbuck] = E; rowptr[N] = E; }
}

// S2: scatter packed (src<<BSH | dst&mask) into bucket regions
__global__ __launch_bounds__(256) void bucket_scatter(
    const void* __restrict__ ei, const int* __restrict__ flag,
    int* __restrict__ bucketCur, uint32_t* __restrict__ packed,
    long E, int chunk, int nbuck) {
  __shared__ int cnt[MAXB];
  __shared__ int base[MAXB];
  __shared__ int cur[MAXB];
  const int is64 = flag[0];
  long beg = (long)blockIdx.x * chunk;
  long end = beg + chunk; if (end > E) end = E;
  for (int i = threadIdx.x; i < nbuck; i += 256) { cnt[i] = 0; cur[i] = 0; }
  __syncthreads();
  for (long e = beg + threadIdx.x; e < end; e += 256)
    atomicAdd(&cnt[load_dst(ei, is64, E, e) >> BSH], 1);
  __syncthreads();
  for (int i = threadIdx.x; i < nbuck; i += 256)
    base[i] = cnt[i] ? atomicAdd(&bucketCur[i], cnt[i]) : 0;
  __syncthreads();
  for (long e = beg + threadIdx.x; e < end; e += 256) {
    int dst = load_dst(ei, is64, E, e);
    int src = load_src(ei, is64, E, e);
    int b = dst >> BSH;
    int off = atomicAdd(&cur[b], 1);
    packed[base[b] + off] = ((uint32_t)src << BSH) | (uint32_t)(dst & ((1 << BSH) - 1));
  }
}

// S3: per bucket -> local hist + scan -> rowptr, invd, contiguous col writes
__global__ __launch_bounds__(256) void bucket_build(
    const uint32_t* __restrict__ packed, const int* __restrict__ bucketPtr,
    int* __restrict__ col, int* __restrict__ rowptr, float* __restrict__ invd,
    int N, int nbuck) {
  __shared__ int lcnt[1 << BSH];
  __shared__ int lbase[1 << BSH];
  __shared__ int lcur[1 << BSH];
  const int b = blockIdx.x;
  const int tid = threadIdx.x;
  const int beg = bucketPtr[b], end = bucketPtr[b + 1];
  if (tid < 128) { lcnt[tid] = 0; lcur[tid] = 0; }
  __syncthreads();
  for (int i = beg + tid; i < end; i += 256)
    atomicAdd(&lcnt[packed[i] & 127], 1);
  __syncthreads();
  if (tid < 128) lbase[tid] = lcnt[tid];
  __syncthreads();
  for (int off = 1; off < 128; off <<= 1) {
    int t = (tid >= off && tid < 128) ? lbase[tid - off] : 0;
    __syncthreads();
    if (tid < 128) lbase[tid] += t;
    __syncthreads();
  }
  if (tid < 128) {
    int excl = lbase[tid] - lcnt[tid];
    lbase[tid] = excl;
    int n = (b << BSH) + tid;
    if (n < N) {
      rowptr[n] = beg + excl;
      int d = lcnt[tid];
      invd[n] = 1.0f / (float)(d > 1 ? d : 1);
    }
  }
  __syncthreads();
  for (int i = beg + tid; i < end; i += 256) {
    uint32_t p = packed[i];
    int l = p & 127;
    int pos = beg + lbase[l] + atomicAdd(&lcur[l], 1);
    col[pos] = (int)(p >> BSH);
  }
}

// ---------------------------------------------------------------------------
// gather-style mean aggregation (bf16 in, fp32 pk accum, bf16 out)
// one wave per node; 16 B/lane -> quarter-wave per source row
// main loop: 16 edges/iter unpredicated; tail: <=15 edges predicated
// optionally generates the packed dropout mask (2 threefry + 2 ballots/wave)
// ---------------------------------------------------------------------------
__global__ __launch_bounds__(256) void agg_kernel(
    const ushort* __restrict__ featb, const int* __restrict__ rowptr,
    const int* __restrict__ col, const float* __restrict__ invd,
    ushort* __restrict__ aggb, unsigned long long* __restrict__ maskb, int N) {
  const int lane = threadIdx.x & 63;
  const int q  = lane >> 4;            // quarter 0..3
  const int sl = lane & 15;            // 16 B slice of the 256 B row
  const uint32_t slb = (uint32_t)sl * 16u;
  int n = (int)(((long)blockIdx.x * blockDim.x + threadIdx.x) >> 6);
  if (n >= N) return;

  if (maskb) {  // dropout mask for node n, packed 128 bits -> 2 x u64
    uint32_t base = (uint32_t)n * 128u;
    bool k0 = keep_bit(base + (uint32_t)lane);
    bool k1 = keep_bit(base + 64u + (uint32_t)lane);
    unsigned long long w0 = __ballot(k0);
    unsigned long long w1 = __ballot(k1);
    if (lane == 0) {
      maskb[2 * n]     = w0;
      maskb[2 * n + 1] = w1;
    }
  }

  const char* xc = (const char*)featb;
  const int beg = rowptr[n], end = rowptr[n + 1];

  f32x2 acc[4];
#pragma unroll
  for (int i = 0; i < 4; i++) acc[i] = (f32x2){0.f, 0.f};

  int e = beg;
  const int fend = beg + ((end - beg) & ~15);   // full 16-edge groups

  for (; e < fend; e += 16) {
    uint32_t o0 = ((uint32_t)col[e + q]      << 8) + slb;
    uint32_t o1 = ((uint32_t)col[e + 4 + q]  << 8) + slb;
    uint32_t o2 = ((uint32_t)col[e + 8 + q]  << 8) + slb;
    uint32_t o3 = ((uint32_t)col[e + 12 + q] << 8) + slb;
    uint4 a = *(const uint4*)(xc + o0);
    uint4 b = *(const uint4*)(xc + o1);
    uint4 c = *(const uint4*)(xc + o2);
    uint4 d = *(const uint4*)(xc + o3);
    acc[0] += bf2f2(a.x); acc[1] += bf2f2(a.y); acc[2] += bf2f2(a.z); acc[3] += bf2f2(a.w);
    acc[0] += bf2f2(b.x); acc[1] += bf2f2(b.y); acc[2] += bf2f2(b.z); acc[3] += bf2f2(b.w);
    acc[0] += bf2f2(c.x); acc[1] += bf2f2(c.y); acc[2] += bf2f2(c.z); acc[3] += bf2f2(c.w);
    acc[0] += bf2f2(d.x); acc[1] += bf2f2(d.y); acc[2] += bf2f2(d.z); acc[3] += bf2f2(d.w);
  }

  for (; e < end; e += 8) {            // tail: at most 2 iterations
    int i0 = e + q, i1 = i0 + 4;
    bool v0 = i0 < end, v1 = i1 < end;
    uint32_t o0 = ((uint32_t)col[v0 ? i0 : beg] << 8) + slb;
    uint32_t o1 = ((uint32_t)col[v1 ? i1 : beg] << 8) + slb;
    uint4 a = *(const uint4*)(xc + o0);
    uint4 b = *(const uint4*)(xc + o1);
    if (v0) {
      acc[0] += bf2f2(a.x); acc[1] += bf2f2(a.y);
      acc[2] += bf2f2(a.z); acc[3] += bf2f2(a.w);
    }
    if (v1) {
      acc[0] += bf2f2(b.x); acc[1] += bf2f2(b.y);
      acc[2] += bf2f2(b.z); acc[3] += bf2f2(b.w);
    }
  }

  // combine the 4 quarter-wave partial sums (lanes with equal sl)
#pragma unroll
  for (int i = 0; i < 4; i++) {
    acc[i].x += __shfl_xor(acc[i].x, 16);
    acc[i].y += __shfl_xor(acc[i].y, 16);
    acc[i].x += __shfl_xor(acc[i].x, 32);
    acc[i].y += __shfl_xor(acc[i].y, 32);
  }

  if (q == 0) {
    float sc = invd[n];
    ushort8 o;
#pragma unroll
    for (int i = 0; i < 4; i++) {
      o[2 * i]     = f2bf(acc[i].x * sc);
      o[2 * i + 1] = f2bf(acc[i].y * sc);
    }
    *(ushort8*)(aggb + (long)n * D_FEAT + sl * 8) = o;
  }
}

// ---------------------------------------------------------------------------
// layer 1 (MFMA, LDS-staged weights): h1d = bf16(dropout(relu([agg|x]@W1+b1)))
// block = 256 = 4 waves, 128 nodes; wave computes 2 tiles of 16 nodes.
// w1t (64 KB) staged in LDS with XOR swizzle byte^=((j&7)<<4) to kill the
// 16-way ds_read_b128 bank conflict (512 B row stride); r16<->r16+8 2-way is free.
// ---------------------------------------------------------------------------
__global__ __launch_bounds__(256) void layer1_kernel(
    const ushort* __restrict__ aggb, const ushort* __restrict__ xb,
    const ushort* __restrict__ w1t, const float* __restrict__ b1,
    const unsigned long long* __restrict__ maskb,
    ushort* __restrict__ h1d, int N) {
  __shared__ ushort w1s[128 * 256];   // 64 KB
  const int tid = threadIdx.x;
  const int lane = tid & 63;
  const int wv = tid >> 6;
  const int r16 = lane & 15;
  const int kg = lane >> 4;

  // stage w1t -> LDS (each thread 16 x dwordx4, contiguous per round)
  {
    const uint32_t swz = ((uint32_t)(tid >> 5) & 7u) << 4;   // = (j&7)<<4
#pragma unroll
    for (int i = 0; i < 16; i++) {
      uint32_t byte = (uint32_t)i * 4096u + (uint32_t)tid * 16u;
      uint4 v = *(const uint4*)((const char*)w1t + byte);
      *(uint4*)((char*)w1s + (byte ^ swz)) = v;
    }
  }
  __syncthreads();

  const int node_base = blockIdx.x * 128 + wv * 32;
  int ar0 = node_base + r16;       if (ar0 >= N) ar0 = N - 1;
  int ar1 = node_base + 16 + r16;  if (ar1 >= N) ar1 = N - 1;

  f32x4 acc0[8], acc1[8];
#pragma unroll
  for (int i = 0; i < 8; i++) {
    acc0[i] = (f32x4){0.f, 0.f, 0.f, 0.f};
    acc1[i] = (f32x4){0.f, 0.f, 0.f, 0.f};
  }

  const ushort* a0g = aggb + (long)ar0 * 128 + kg * 8;
  const ushort* a0x = xb   + (long)ar0 * 128 + kg * 8;
  const ushort* a1g = aggb + (long)ar1 * 128 + kg * 8;
  const ushort* a1x = xb   + (long)ar1 * 128 + kg * 8;
  const uint32_t rswz = ((uint32_t)(r16 & 7)) << 4;

#pragma unroll
  for (int s = 0; s < 8; s++) {
    short8 aT0 = (s < 4) ? *(const short8*)(a0g + s * 32)
                         : *(const short8*)(a0x + (s - 4) * 32);
    short8 aT1 = (s < 4) ? *(const short8*)(a1g + s * 32)
                         : *(const short8*)(a1x + (s - 4) * 32);
#pragma unroll
    for (int ct = 0; ct < 8; ct++) {
      uint32_t boff = ((uint32_t)(ct * 16 + r16) * 512u +
                       (uint32_t)s * 64u + (uint32_t)kg * 16u) ^ rswz;
      short8 b = *(const short8*)((const char*)w1s + boff);
      acc0[ct] = __builtin_amdgcn_mfma_f32_16x16x32_bf16(aT0, b, acc0[ct], 0, 0, 0);
      acc1[ct] = __builtin_amdgcn_mfma_f32_16x16x32_bf16(aT1, b, acc1[ct], 0, 0, 0);
    }
  }

  float bbv[8];
#pragma unroll
  for (int ct = 0; ct < 8; ct++) bbv[ct] = b1[ct * 16 + r16];

#pragma unroll
  for (int t = 0; t < 2; t++) {
    const f32x4* acc = t ? acc1 : acc0;
    int nb = node_base + t * 16;
#pragma unroll
    for (int r = 0; r < 4; r++) {
      int n = nb + kg * 4 + r;
      if (n < N) {
        unsigned long long m0 = maskb[2 * n];
        unsigned long long m1 = maskb[2 * n + 1];
#pragma unroll
        for (int ct = 0; ct < 8; ct++) {
          int j = ct * 16 + r16;
          float h = fmaxf(acc[ct][r] + bbv[ct], 0.f);
          unsigned long long w = (j & 64) ? m1 : m0;
          bool keep = (w >> (j & 63)) & 1ull;
          h1d[(long)n * 128 + j] = keep ? f2bf(2.0f * h) : (ushort)0;
        }
      }
    }
  }
}

// ---------------------------------------------------------------------------
// layer 2 (MFMA, LDS-staged weights) + log_softmax
// block = 256 = 4 waves, 128 nodes; wave computes 2 tiles of 16 nodes.
// ---------------------------------------------------------------------------
__global__ __launch_bounds__(256) void layer2_kernel(
    const ushort* __restrict__ aggb, const ushort* __restrict__ h1d,
    const ushort* __restrict__ w2t, const float* __restrict__ b2,
    float* __restrict__ out, int N) {
  __shared__ ushort w2s[64 * 256];    // 32 KB
  const int tid = threadIdx.x;
  const int lane = tid & 63;
  const int wv = tid >> 6;
  const int r16 = lane & 15;
  const int kg = lane >> 4;

  {
    const uint32_t swz = ((uint32_t)(tid >> 5) & 7u) << 4;
#pragma unroll
    for (int i = 0; i < 8; i++) {
      uint32_t byte = (uint32_t)i * 4096u + (uint32_t)tid * 16u;
      uint4 v = *(const uint4*)((const char*)w2t + byte);
      *(uint4*)((char*)w2s + (byte ^ swz)) = v;
    }
  }
  __syncthreads();

  const int node_base = blockIdx.x * 128 + wv * 32;
  int ar0 = node_base + r16;       if (ar0 >= N) ar0 = N - 1;
  int ar1 = node_base + 16 + r16;  if (ar1 >= N) ar1 = N - 1;

  f32x4 acc0[4], acc1[4];
#pragma unroll
  for (int i = 0; i < 4; i++) {
    acc0[i] = (f32x4){0.f, 0.f, 0.f, 0.f};
    acc1[i] = (f32x4){0.f, 0.f, 0.f, 0.f};
  }

  const ushort* a0g = aggb + (long)ar0 * 128 + kg * 8;
  const ushort* a0h = h1d  + (long)ar0 * 128 + kg * 8;
  const ushort* a1g = aggb + (long)ar1 * 128 + kg * 8;
  const ushort* a1h = h1d  + (long)ar1 * 128 + kg * 8;
  const uint32_t rswz = ((uint32_t)(r16 & 7)) << 4;

#pragma unroll
  for (int s = 0; s < 8; s++) {
    short8 aT0 = (s < 4) ? *(const short8*)(a0g + s * 32)
                         : *(const short8*)(a0h + (s - 4) * 32);
    short8 aT1 = (s < 4) ? *(const short8*)(a1g + s * 32)
                         : *(const short8*)(a1h + (s - 4) * 32);
#pragma unroll
    for (int ct = 0; ct < 4; ct++) {
      uint32_t boff = ((uint32_t)(ct * 16 + r16) * 512u +
                       (uint32_t)s * 64u + (uint32_t)kg * 16u) ^ rswz;
      short8 b = *(const short8*)((const char*)w2s + boff);
      acc0[ct] = __builtin_amdgcn_mfma_f32_16x16x32_bf16(aT0, b, acc0[ct], 0, 0, 0);
      acc1[ct] = __builtin_amdgcn_mfma_f32_16x16x32_bf16(aT1, b, acc1[ct], 0, 0, 0);
    }
  }

  float bb[4];
#pragma unroll
  for (int ct = 0; ct < 4; ct++) bb[ct] = b2[ct * 16 + r16];

#pragma unroll
  for (int t = 0; t < 2; t++) {
    const f32x4* acc = t ? acc1 : acc0;
    int nb = node_base + t * 16;
#pragma unroll
    for (int r = 0; r < 4; r++) {
      float v[4];
#pragma unroll
      for (int ct = 0; ct < 4; ct++) v[ct] = acc[ct][r] + bb[ct];
      float m = fmaxf(fmaxf(v[0], v[1]), fmaxf(v[2], v[3]));
#pragma unroll
      for (int off = 1; off < 16; off <<= 1) m = fmaxf(m, __shfl_xor(m, off));
      float s = expf(v[0] - m) + expf(v[1] - m) + expf(v[2] - m) + expf(v[3] - m);
#pragma unroll
      for (int off = 1; off < 16; off <<= 1) s += __shfl_xor(s, off);
      float ls = logf(s);
      int n = nb + kg * 4 + r;
      if (n < N) {
#pragma unroll
        for (int ct = 0; ct < 4; ct++)
          out[(long)n * 64 + ct * 16 + r16] = v[ct] - m - ls;
      }
    }
  }
}

// ---------------------------------------------------------------------------
extern "C" void kernel_launch(void* const* d_in, const int* in_sizes, int n_in,
                              void* d_out, int out_size, void* d_ws, size_t ws_size,
                              hipStream_t stream) {
  const float* x   = (const float*)d_in[0];
  const void*  ei  = d_in[1];
  const float* W1l = (const float*)d_in[2];
  const float* b1  = (const float*)d_in[3];
  const float* W1r = (const float*)d_in[4];
  const float* W2l = (const float*)d_in[5];
  const float* b2  = (const float*)d_in[6];
  const float* W2r = (const float*)d_in[7];
  float* out = (float*)d_out;

  const int  N  = in_sizes[0] / D_FEAT;    // 100000
  const long E  = (long)in_sizes[1] / 2;   // 1600000
  const long NF = (long)N * D_FEAT;        // 12.8M
  const int  nbuck = (N + (1 << BSH) - 1) >> BSH;   // 782

  char* ws = (char*)d_ws;
  size_t off = 0;
  auto alloc = [&](size_t bytes) -> void* {
    void* p = ws + off;
    off = (off + bytes + 255) & ~(size_t)255;
    return p;
  };
  int*      bucketCnt = (int*)alloc(sizeof(int) * MAXB);
  int*      bucketPtr = (int*)alloc(sizeof(int) * (MAXB + 1));
  int*      bucketCur = (int*)alloc(sizeof(int) * MAXB);
  int*      rowptr    = (int*)alloc(sizeof(int) * (N + 1));
  int*      col       = (int*)alloc(sizeof(int) * E);
  uint32_t* packed    = (uint32_t*)alloc(sizeof(uint32_t) * E);
  float*    invd      = (float*)alloc(sizeof(float) * N);
  ushort*   xb        = (ushort*)alloc(sizeof(ushort) * NF);
  ushort*   aggb      = (ushort*)alloc(sizeof(ushort) * NF);
  ushort*   h1d       = (ushort*)alloc(sizeof(ushort) * NF);
  ushort*   w1t       = (ushort*)alloc(sizeof(ushort) * 128 * 256);
  ushort*   w2t       = (ushort*)alloc(sizeof(ushort) * 64 * 256);
  unsigned long long* maskb = (unsigned long long*)alloc(sizeof(unsigned long long) * 2 * N);
  int*      flag      = (int*)alloc(sizeof(int));

  const int chunkE = (int)((E + 255) / 256);   // edges per block, 256 blocks

  hipMemsetAsync(bucketCnt, 0, sizeof(int) * MAXB, stream);

  detect_kernel<<<1, 64, 0, stream>>>((const uint32_t*)ei, flag);
  convx_kernel<<<(int)((NF / 4 + 255) / 256), 256, 0, stream>>>((const float4*)x, xb, NF / 4);
  packw1_kernel<<<128, 256, 0, stream>>>(W1l, W1r, w1t);
  packw2_kernel<<<64, 256, 0, stream>>>(W2l, W2r, w2t);

  bucket_hist<<<256, 256, 0, stream>>>(ei, flag, bucketCnt, E, chunkE, nbuck);
  bucket_scan<<<1, 1024, 0, stream>>>(bucketCnt, bucketPtr, bucketCur, rowptr, N, nbuck, (int)E);
  bucket_scatter<<<256, 256, 0, stream>>>(ei, flag, bucketCur, packed, E, chunkE, nbuck);
  bucket_build<<<nbuck, 256, 0, stream>>>(packed, bucketPtr, col, rowptr, invd, N, nbuck);

  const int aggBlocks = (int)(((long)N * 64 + 255) / 256);
  const int gemmBlocks = (N + 127) / 128;   // 782

  agg_kernel<<<aggBlocks, 256, 0, stream>>>(xb, rowptr, col, invd, aggb, maskb, N);
  layer1_kernel<<<gemmBlocks, 256, 0, stream>>>(aggb, xb, w1t, b1, maskb, h1d, N);

  agg_kernel<<<aggBlocks, 256, 0, stream>>>(h1d, rowptr, col, invd, aggb, nullptr, N);
  layer2_kernel<<<gemmBlocks, 256, 0, stream>>>(aggb, h1d, w2t, b2, out, N);
}

// Round 10
// 238.386 us; speedup vs baseline: 1.6259x; 1.0145x over previous
//
#include <hip/hip_runtime.h>
#include <stdint.h>

#define D_FEAT 128
#define D_OUT  64
#define BSH 7              // 128 nodes per bucket
#define MAXB 1024          // max buckets (N <= 131072)

typedef __attribute__((ext_vector_type(8))) short short8;   // 8 bf16 (4 VGPRs)
typedef __attribute__((ext_vector_type(8))) ushort ushort8; // 8 bf16
typedef __attribute__((ext_vector_type(4))) float f32x4;
typedef __attribute__((ext_vector_type(2))) float f32x2;

// ---------------------------------------------------------------------------
// helpers
// ---------------------------------------------------------------------------
__device__ __forceinline__ ushort f2bf(float f) {            // RNE f32->bf16
  uint32_t u = __float_as_uint(f);
  return (ushort)((u + 0x7FFFu + ((u >> 16) & 1u)) >> 16);
}
// accumulate a packed bf16 pair into an f32x2 (one v_pk_add_f32).
// hi half uses as_float(w) directly: the 16 low garbage bits are < 1 bf16 ULP
// (magnitude bias ~2^-9 rel, sign-preserving) -- negligible vs bf16 rounding.
__device__ __forceinline__ void acc2(f32x2& a, uint32_t w) {
  f32x2 t;
  t.x = __uint_as_float(w << 16);
  t.y = __uint_as_float(w);
  a += t;
}

__device__ __forceinline__ void threefry2x32(uint32_t k0, uint32_t k1,
                                             uint32_t& x0, uint32_t& x1) {
  uint32_t k2 = k0 ^ k1 ^ 0x1BD11BDAu;
#define TF_ROT(r) { x0 += x1; x1 = (x1 << (r)) | (x1 >> (32 - (r))); x1 ^= x0; }
  x0 += k0; x1 += k1;
  TF_ROT(13) TF_ROT(15) TF_ROT(26) TF_ROT(6)
  x0 += k1; x1 += k2 + 1u;
  TF_ROT(17) TF_ROT(29) TF_ROT(16) TF_ROT(24)
  x0 += k2; x1 += k0 + 2u;
  TF_ROT(13) TF_ROT(15) TF_ROT(26) TF_ROT(6)
  x0 += k0; x1 += k1 + 3u;
  TF_ROT(17) TF_ROT(29) TF_ROT(16) TF_ROT(24)
  x0 += k1; x1 += k2 + 4u;
  TF_ROT(13) TF_ROT(15) TF_ROT(26) TF_ROT(6)
  x0 += k2; x1 += k0 + 5u;
#undef TF_ROT
}

// keep iff top bit of (r0^r1) of threefry2x32((0,42), (0, i)) is 0
__device__ __forceinline__ bool keep_bit(uint32_t i) {
  uint32_t t0 = 0u, t1 = i;
  threefry2x32(0u, 42u, t0, t1);
  return (((t0 ^ t1) >> 31) == 0u);
}

// ---------------------------------------------------------------------------
// edge_index dtype detection: int64 rows => all odd u32 words are zero
// ---------------------------------------------------------------------------
__global__ void detect_kernel(const uint32_t* __restrict__ ei, int* __restrict__ flag) {
  uint32_t v = ei[2 * threadIdx.x + 1];
  unsigned long long nz = __ballot(v != 0u);
  if (threadIdx.x == 0) flag[0] = (nz == 0ull) ? 1 : 0;
}

__device__ __forceinline__ int load_dst(const void* ei, int is64, long E, long e) {
  return is64 ? (int)((const long long*)ei)[E + e] : ((const int*)ei)[E + e];
}
__device__ __forceinline__ int load_src(const void* ei, int is64, long E, long e) {
  return is64 ? (int)((const long long*)ei)[e] : ((const int*)ei)[e];
}

// ---------------------------------------------------------------------------
// input conversions / weight packing
// ---------------------------------------------------------------------------
__global__ __launch_bounds__(256) void convx_kernel(
    const float4* __restrict__ x, ushort* __restrict__ xb, long n4) {
  long i = (long)blockIdx.x * blockDim.x + threadIdx.x;
  if (i >= n4) return;
  float4 v = x[i];
  ushort4 o = {f2bf(v.x), f2bf(v.y), f2bf(v.z), f2bf(v.w)};
  *(ushort4*)(xb + i * 4) = o;
}

// w1t[j][k] = bf16(k<128 ? W1l[k][j] : W1r[k-128][j]),  j<128, k<256
__global__ __launch_bounds__(256) void packw1_kernel(
    const float* __restrict__ Wl, const float* __restrict__ Wr,
    ushort* __restrict__ wt) {
  int idx = blockIdx.x * blockDim.x + threadIdx.x;   // 128*256
  if (idx >= 128 * 256) return;
  int j = idx >> 8, k = idx & 255;
  float v = (k < 128) ? Wl[k * 128 + j] : Wr[(k - 128) * 128 + j];
  wt[j * 256 + k] = f2bf(v);
}

// w2t[j][k] = bf16(k<128 ? W2l[k][j] : W2r[k-128][j]),  j<64, k<256
__global__ __launch_bounds__(256) void packw2_kernel(
    const float* __restrict__ Wl, const float* __restrict__ Wr,
    ushort* __restrict__ wt) {
  int idx = blockIdx.x * blockDim.x + threadIdx.x;   // 64*256
  if (idx >= 64 * 256) return;
  int j = idx >> 8, k = idx & 255;
  float v = (k < 128) ? Wl[k * 64 + j] : Wr[(k - 128) * 64 + j];
  wt[j * 256 + k] = f2bf(v);
}

// zero out the phantom row N of a bf16 feature buffer (256 B)
__global__ void zrow_kernel(ushort* __restrict__ b0, ushort* __restrict__ b1, int N) {
  ushort8 z = (ushort8){0, 0, 0, 0, 0, 0, 0, 0};
  if (threadIdx.x < 16) *(ushort8*)(b0 + (long)N * D_FEAT + threadIdx.x * 8) = z;
  else *(ushort8*)(b1 + (long)N * D_FEAT + (threadIdx.x - 16) * 8) = z;
}

// ---------------------------------------------------------------------------
// CSR build via bucketed counting sort (no random 4B scatter)
// ---------------------------------------------------------------------------
__global__ __launch_bounds__(256) void bucket_hist(
    const void* __restrict__ ei, const int* __restrict__ flag,
    int* __restrict__ bucketCnt, long E, int chunk, int nbuck) {
  __shared__ int cnt[MAXB];
  const int is64 = flag[0];
  long beg = (long)blockIdx.x * chunk;
  long end = beg + chunk; if (end > E) end = E;
  for (int i = threadIdx.x; i < nbuck; i += 256) cnt[i] = 0;
  __syncthreads();
  for (long e = beg + threadIdx.x; e < end; e += 256)
    atomicAdd(&cnt[load_dst(ei, is64, E, e) >> BSH], 1);
  __syncthreads();
  for (int i = threadIdx.x; i < nbuck; i += 256)
    if (cnt[i]) atomicAdd(&bucketCnt[i], cnt[i]);
}

// scan buckets (single block, 1024 threads); also seeds cursors & rowptr[N]
__global__ __launch_bounds__(1024) void bucket_scan(
    const int* __restrict__ bucketCnt, int* __restrict__ bucketPtr,
    int* __restrict__ bucketCur, int* __restrict__ rowptr,
    int N, int nbuck, int E) {
  __shared__ int ts[1024];
  int tid = threadIdx.x;
  int v = (tid < nbuck) ? bucketCnt[tid] : 0;
  ts[tid] = v;
  __syncthreads();
  for (int off = 1; off < 1024; off <<= 1) {
    int t = (tid >= off) ? ts[tid - off] : 0;
    __syncthreads();
    ts[tid] += t;
    __syncthreads();
  }
  if (tid < nbuck) {
    int excl = ts[tid] - v;
    bucketPtr[tid] = excl;
    bucketCur[tid] = excl;
  }
  if (tid == 0) { bucketPtr[nbuck] = E; rowptr[N] = E; }
}

// S2: scatter packed (src<<BSH | dst&mask) into bucket regions
__global__ __launch_bounds__(256) void bucket_scatter(
    const void* __restrict__ ei, const int* __restrict__ flag,
    int* __restrict__ bucketCur, uint32_t* __restrict__ packed,
    long E, int chunk, int nbuck) {
  __shared__ int cnt[MAXB];
  __shared__ int base[MAXB];
  __shared__ int cur[MAXB];
  const int is64 = flag[0];
  long beg = (long)blockIdx.x * chunk;
  long end = beg + chunk; if (end > E) end = E;
  for (int i = threadIdx.x; i < nbuck; i += 256) { cnt[i] = 0; cur[i] = 0; }
  __syncthreads();
  for (long e = beg + threadIdx.x; e < end; e += 256)
    atomicAdd(&cnt[load_dst(ei, is64, E, e) >> BSH], 1);
  __syncthreads();
  for (int i = threadIdx.x; i < nbuck; i += 256)
    base[i] = cnt[i] ? atomicAdd(&bucketCur[i], cnt[i]) : 0;
  __syncthreads();
  for (long e = beg + threadIdx.x; e < end; e += 256) {
    int dst = load_dst(ei, is64, E, e);
    int src = load_src(ei, is64, E, e);
    int b = dst >> BSH;
    int off = atomicAdd(&cur[b], 1);
    packed[base[b] + off] = ((uint32_t)src << BSH) | (uint32_t)(dst & ((1 << BSH) - 1));
  }
}

// S3: per bucket -> local hist + scan -> rowptr, invd, contiguous col writes
__global__ __launch_bounds__(256) void bucket_build(
    const uint32_t* __restrict__ packed, const int* __restrict__ bucketPtr,
    int* __restrict__ col, int* __restrict__ rowptr, float* __restrict__ invd,
    int N, int nbuck) {
  __shared__ int lcnt[1 << BSH];
  __shared__ int lbase[1 << BSH];
  __shared__ int lcur[1 << BSH];
  const int b = blockIdx.x;
  const int tid = threadIdx.x;
  const int beg = bucketPtr[b], end = bucketPtr[b + 1];
  if (tid < 128) { lcnt[tid] = 0; lcur[tid] = 0; }
  __syncthreads();
  for (int i = beg + tid; i < end; i += 256)
    atomicAdd(&lcnt[packed[i] & 127], 1);
  __syncthreads();
  if (tid < 128) lbase[tid] = lcnt[tid];
  __syncthreads();
  for (int off = 1; off < 128; off <<= 1) {
    int t = (tid >= off && tid < 128) ? lbase[tid - off] : 0;
    __syncthreads();
    if (tid < 128) lbase[tid] += t;
    __syncthreads();
  }
  if (tid < 128) {
    int excl = lbase[tid] - lcnt[tid];
    lbase[tid] = excl;
    int n = (b << BSH) + tid;
    if (n < N) {
      rowptr[n] = beg + excl;
      int d = lcnt[tid];
      invd[n] = 1.0f / (float)(d > 1 ? d : 1);
    }
  }
  __syncthreads();
  for (int i = beg + tid; i < end; i += 256) {
    uint32_t p = packed[i];
    int l = p & 127;
    int pos = beg + lbase[l] + atomicAdd(&lcur[l], 1);
    col[pos] = (int)(p >> BSH);
  }
}

// ---------------------------------------------------------------------------
// gather-style mean aggregation (bf16 in, fp32 pk accum, bf16 out)
// one wave per node; 16 B/lane -> quarter-wave per source row, 16 edges/iter
// branch-free: OOB edge slots select the zero-row (row N) offset via cndmask
// optionally generates the packed dropout mask (2 threefry + 2 ballots/wave)
// ---------------------------------------------------------------------------
__global__ __launch_bounds__(256) void agg_kernel(
    const ushort* __restrict__ featb, const int* __restrict__ rowptr,
    const int* __restrict__ col, const float* __restrict__ invd,
    ushort* __restrict__ aggb, unsigned long long* __restrict__ maskb, int N) {
  const int lane = threadIdx.x & 63;
  const int q  = lane >> 4;            // quarter 0..3
  const int sl = lane & 15;            // 16 B slice of the 256 B row
  const uint32_t slb = (uint32_t)sl * 16u;
  int n = (int)(((long)blockIdx.x * blockDim.x + threadIdx.x) >> 6);
  if (n >= N) return;

  if (maskb) {  // dropout mask for node n, packed 128 bits -> 2 x u64
    uint32_t base = (uint32_t)n * 128u;
    bool k0 = keep_bit(base + (uint32_t)lane);
    bool k1 = keep_bit(base + 64u + (uint32_t)lane);
    unsigned long long w0 = __ballot(k0);
    unsigned long long w1 = __ballot(k1);
    if (lane == 0) {
      maskb[2 * n]     = w0;
      maskb[2 * n + 1] = w1;
    }
  }

  const char* xc = (const char*)featb;
  const int beg = rowptr[n], end = rowptr[n + 1];
  const uint32_t zoff = ((uint32_t)N << 8) + slb;   // zero-row offset

  f32x2 acc[4];
#pragma unroll
  for (int i = 0; i < 4; i++) acc[i] = (f32x2){0.f, 0.f};

  for (int e = beg + q; e < end; e += 16) {
    // col[] has >=16 slack entries; value unused when slot is OOB
    int c0 = col[e], c1 = col[e + 4], c2 = col[e + 8], c3 = col[e + 12];
    uint32_t o0 = (e      < end) ? (((uint32_t)c0 << 8) + slb) : zoff;
    uint32_t o1 = (e + 4  < end) ? (((uint32_t)c1 << 8) + slb) : zoff;
    uint32_t o2 = (e + 8  < end) ? (((uint32_t)c2 << 8) + slb) : zoff;
    uint32_t o3 = (e + 12 < end) ? (((uint32_t)c3 << 8) + slb) : zoff;
    uint4 a = *(const uint4*)(xc + o0);
    uint4 b = *(const uint4*)(xc + o1);
    uint4 c = *(const uint4*)(xc + o2);
    uint4 d = *(const uint4*)(xc + o3);
    acc2(acc[0], a.x); acc2(acc[1], a.y); acc2(acc[2], a.z); acc2(acc[3], a.w);
    acc2(acc[0], b.x); acc2(acc[1], b.y); acc2(acc[2], b.z); acc2(acc[3], b.w);
    acc2(acc[0], c.x); acc2(acc[1], c.y); acc2(acc[2], c.z); acc2(acc[3], c.w);
    acc2(acc[0], d.x); acc2(acc[1], d.y); acc2(acc[2], d.z); acc2(acc[3], d.w);
  }

  // combine the 4 quarter-wave partial sums (lanes with equal sl)
#pragma unroll
  for (int i = 0; i < 4; i++) {
    acc[i].x += __shfl_xor(acc[i].x, 16);
    acc[i].y += __shfl_xor(acc[i].y, 16);
    acc[i].x += __shfl_xor(acc[i].x, 32);
    acc[i].y += __shfl_xor(acc[i].y, 32);
  }

  if (q == 0) {
    float sc = invd[n];
    ushort8 o;
#pragma unroll
    for (int i = 0; i < 4; i++) {
      o[2 * i]     = f2bf(acc[i].x * sc);
      o[2 * i + 1] = f2bf(acc[i].y * sc);
    }
    *(ushort8*)(aggb + (long)n * D_FEAT + sl * 8) = o;
  }
}

// ---------------------------------------------------------------------------
// layer 1 (MFMA, LDS-staged weights): h1d = bf16(dropout(relu([agg|x]@W1+b1)))
// block = 256 = 4 waves, 128 nodes; wave computes 2 tiles of 16 nodes.
// w1t (64 KB) staged in LDS with XOR swizzle byte^=((j&7)<<4) to kill the
// 16-way ds_read_b128 bank conflict (512 B row stride); r16<->r16+8 2-way is free.
// ---------------------------------------------------------------------------
__global__ __launch_bounds__(256) void layer1_kernel(
    const ushort* __restrict__ aggb, const ushort* __restrict__ xb,
    const ushort* __restrict__ w1t, const float* __restrict__ b1,
    const unsigned long long* __restrict__ maskb,
    ushort* __restrict__ h1d, int N) {
  __shared__ ushort w1s[128 * 256];   // 64 KB
  const int tid = threadIdx.x;
  const int lane = tid & 63;
  const int wv = tid >> 6;
  const int r16 = lane & 15;
  const int kg = lane >> 4;

  // stage w1t -> LDS (each thread 16 x dwordx4, contiguous per round)
  {
    const uint32_t swz = ((uint32_t)(tid >> 5) & 7u) << 4;   // = (j&7)<<4
#pragma unroll
    for (int i = 0; i < 16; i++) {
      uint32_t byte = (uint32_t)i * 4096u + (uint32_t)tid * 16u;
      uint4 v = *(const uint4*)((const char*)w1t + byte);
      *(uint4*)((char*)w1s + (byte ^ swz)) = v;
    }
  }
  __syncthreads();

  const int node_base = blockIdx.x * 128 + wv * 32;
  int ar0 = node_base + r16;       if (ar0 >= N) ar0 = N - 1;
  int ar1 = node_base + 16 + r16;  if (ar1 >= N) ar1 = N - 1;

  f32x4 acc0[8], acc1[8];
#pragma unroll
  for (int i = 0; i < 8; i++) {
    acc0[i] = (f32x4){0.f, 0.f, 0.f, 0.f};
    acc1[i] = (f32x4){0.f, 0.f, 0.f, 0.f};
  }

  const ushort* a0g = aggb + (long)ar0 * 128 + kg * 8;
  const ushort* a0x = xb   + (long)ar0 * 128 + kg * 8;
  const ushort* a1g = aggb + (long)ar1 * 128 + kg * 8;
  const ushort* a1x = xb   + (long)ar1 * 128 + kg * 8;
  const uint32_t rswz = ((uint32_t)(r16 & 7)) << 4;

#pragma unroll
  for (int s = 0; s < 8; s++) {
    short8 aT0 = (s < 4) ? *(const short8*)(a0g + s * 32)
                         : *(const short8*)(a0x + (s - 4) * 32);
    short8 aT1 = (s < 4) ? *(const short8*)(a1g + s * 32)
                         : *(const short8*)(a1x + (s - 4) * 32);
#pragma unroll
    for (int ct = 0; ct < 8; ct++) {
      uint32_t boff = ((uint32_t)(ct * 16 + r16) * 512u +
                       (uint32_t)s * 64u + (uint32_t)kg * 16u) ^ rswz;
      short8 b = *(const short8*)((const char*)w1s + boff);
      acc0[ct] = __builtin_amdgcn_mfma_f32_16x16x32_bf16(aT0, b, acc0[ct], 0, 0, 0);
      acc1[ct] = __builtin_amdgcn_mfma_f32_16x16x32_bf16(aT1, b, acc1[ct], 0, 0, 0);
    }
  }

  float bbv[8];
#pragma unroll
  for (int ct = 0; ct < 8; ct++) bbv[ct] = b1[ct * 16 + r16];

#pragma unroll
  for (int t = 0; t < 2; t++) {
    const f32x4* acc = t ? acc1 : acc0;
    int nb = node_base + t * 16;
#pragma unroll
    for (int r = 0; r < 4; r++) {
      int n = nb + kg * 4 + r;
      if (n < N) {
        unsigned long long m0 = maskb[2 * n];
        unsigned long long m1 = maskb[2 * n + 1];
#pragma unroll
        for (int ct = 0; ct < 8; ct++) {
          int j = ct * 16 + r16;
          float h = fmaxf(acc[ct][r] + bbv[ct], 0.f);
          unsigned long long w = (j & 64) ? m1 : m0;
          bool keep = (w >> (j & 63)) & 1ull;
          h1d[(long)n * 128 + j] = keep ? f2bf(2.0f * h) : (ushort)0;
        }
      }
    }
  }
}

// ---------------------------------------------------------------------------
// layer 2 (MFMA, LDS-staged weights) + log_softmax
// block = 256 = 4 waves, 128 nodes; wave computes 2 tiles of 16 nodes.
// ---------------------------------------------------------------------------
__global__ __launch_bounds__(256) void layer2_kernel(
    const ushort* __restrict__ aggb, const ushort* __restrict__ h1d,
    const ushort* __restrict__ w2t, const float* __restrict__ b2,
    float* __restrict__ out, int N) {
  __shared__ ushort w2s[64 * 256];    // 32 KB
  const int tid = threadIdx.x;
  const int lane = tid & 63;
  const int wv = tid >> 6;
  const int r16 = lane & 15;
  const int kg = lane >> 4;

  {
    const uint32_t swz = ((uint32_t)(tid >> 5) & 7u) << 4;
#pragma unroll
    for (int i = 0; i < 8; i++) {
      uint32_t byte = (uint32_t)i * 4096u + (uint32_t)tid * 16u;
      uint4 v = *(const uint4*)((const char*)w2t + byte);
      *(uint4*)((char*)w2s + (byte ^ swz)) = v;
    }
  }
  __syncthreads();

  const int node_base = blockIdx.x * 128 + wv * 32;
  int ar0 = node_base + r16;       if (ar0 >= N) ar0 = N - 1;
  int ar1 = node_base + 16 + r16;  if (ar1 >= N) ar1 = N - 1;

  f32x4 acc0[4], acc1[4];
#pragma unroll
  for (int i = 0; i < 4; i++) {
    acc0[i] = (f32x4){0.f, 0.f, 0.f, 0.f};
    acc1[i] = (f32x4){0.f, 0.f, 0.f, 0.f};
  }

  const ushort* a0g = aggb + (long)ar0 * 128 + kg * 8;
  const ushort* a0h = h1d  + (long)ar0 * 128 + kg * 8;
  const ushort* a1g = aggb + (long)ar1 * 128 + kg * 8;
  const ushort* a1h = h1d  + (long)ar1 * 128 + kg * 8;
  const uint32_t rswz = ((uint32_t)(r16 & 7)) << 4;

#pragma unroll
  for (int s = 0; s < 8; s++) {
    short8 aT0 = (s < 4) ? *(const short8*)(a0g + s * 32)
                         : *(const short8*)(a0h + (s - 4) * 32);
    short8 aT1 = (s < 4) ? *(const short8*)(a1g + s * 32)
                         : *(const short8*)(a1h + (s - 4) * 32);
#pragma unroll
    for (int ct = 0; ct < 4; ct++) {
      uint32_t boff = ((uint32_t)(ct * 16 + r16) * 512u +
                       (uint32_t)s * 64u + (uint32_t)kg * 16u) ^ rswz;
      short8 b = *(const short8*)((const char*)w2s + boff);
      acc0[ct] = __builtin_amdgcn_mfma_f32_16x16x32_bf16(aT0, b, acc0[ct], 0, 0, 0);
      acc1[ct] = __builtin_amdgcn_mfma_f32_16x16x32_bf16(aT1, b, acc1[ct], 0, 0, 0);
    }
  }

  float bb[4];
#pragma unroll
  for (int ct = 0; ct < 4; ct++) bb[ct] = b2[ct * 16 + r16];

#pragma unroll
  for (int t = 0; t < 2; t++) {
    const f32x4* acc = t ? acc1 : acc0;
    int nb = node_base + t * 16;
#pragma unroll
    for (int r = 0; r < 4; r++) {
      float v[4];
#pragma unroll
      for (int ct = 0; ct < 4; ct++) v[ct] = acc[ct][r] + bb[ct];
      float m = fmaxf(fmaxf(v[0], v[1]), fmaxf(v[2], v[3]));
#pragma unroll
      for (int off = 1; off < 16; off <<= 1) m = fmaxf(m, __shfl_xor(m, off));
      float s = expf(v[0] - m) + expf(v[1] - m) + expf(v[2] - m) + expf(v[3] - m);
#pragma unroll
      for (int off = 1; off < 16; off <<= 1) s += __shfl_xor(s, off);
      float ls = logf(s);
      int n = nb + kg * 4 + r;
      if (n < N) {
#pragma unroll
        for (int ct = 0; ct < 4; ct++)
          out[(long)n * 64 + ct * 16 + r16] = v[ct] - m - ls;
      }
    }
  }
}

// ---------------------------------------------------------------------------
extern "C" void kernel_launch(void* const* d_in, const int* in_sizes, int n_in,
                              void* d_out, int out_size, void* d_ws, size_t ws_size,
                              hipStream_t stream) {
  const float* x   = (const float*)d_in[0];
  const void*  ei  = d_in[1];
  const float* W1l = (const float*)d_in[2];
  const float* b1  = (const float*)d_in[3];
  const float* W1r = (const float*)d_in[4];
  const float* W2l = (const float*)d_in[5];
  const float* b2  = (const float*)d_in[6];
  const float* W2r = (const float*)d_in[7];
  float* out = (float*)d_out;

  const int  N  = in_sizes[0] / D_FEAT;    // 100000
  const long E  = (long)in_sizes[1] / 2;   // 1600000
  const long NF = (long)N * D_FEAT;        // 12.8M
  const int  nbuck = (N + (1 << BSH) - 1) >> BSH;   // 782

  char* ws = (char*)d_ws;
  size_t off = 0;
  auto alloc = [&](size_t bytes) -> void* {
    void* p = ws + off;
    off = (off + bytes + 255) & ~(size_t)255;
    return p;
  };
  int*      bucketCnt = (int*)alloc(sizeof(int) * MAXB);
  int*      bucketPtr = (int*)alloc(sizeof(int) * (MAXB + 1));
  int*      bucketCur = (int*)alloc(sizeof(int) * MAXB);
  int*      rowptr    = (int*)alloc(sizeof(int) * (N + 1));
  int*      col       = (int*)alloc(sizeof(int) * (E + 16));      // +16 slack
  uint32_t* packed    = (uint32_t*)alloc(sizeof(uint32_t) * E);
  float*    invd      = (float*)alloc(sizeof(float) * N);
  ushort*   xb        = (ushort*)alloc(sizeof(ushort) * (NF + D_FEAT));  // +zero row
  ushort*   aggb      = (ushort*)alloc(sizeof(ushort) * NF);
  ushort*   h1d       = (ushort*)alloc(sizeof(ushort) * (NF + D_FEAT)); // +zero row
  ushort*   w1t       = (ushort*)alloc(sizeof(ushort) * 128 * 256);
  ushort*   w2t       = (ushort*)alloc(sizeof(ushort) * 64 * 256);
  unsigned long long* maskb = (unsigned long long*)alloc(sizeof(unsigned long long) * 2 * N);
  int*      flag      = (int*)alloc(sizeof(int));

  const int chunkE = (int)((E + 255) / 256);   // edges per block, 256 blocks

  hipMemsetAsync(bucketCnt, 0, sizeof(int) * MAXB, stream);

  detect_kernel<<<1, 64, 0, stream>>>((const uint32_t*)ei, flag);
  convx_kernel<<<(int)((NF / 4 + 255) / 256), 256, 0, stream>>>((const float4*)x, xb, NF / 4);
  zrow_kernel<<<1, 32, 0, stream>>>(xb, h1d, N);
  packw1_kernel<<<128, 256, 0, stream>>>(W1l, W1r, w1t);
  packw2_kernel<<<64, 256, 0, stream>>>(W2l, W2r, w2t);

  bucket_hist<<<256, 256, 0, stream>>>(ei, flag, bucketCnt, E, chunkE, nbuck);
  bucket_scan<<<1, 1024, 0, stream>>>(bucketCnt, bucketPtr, bucketCur, rowptr, N, nbuck, (int)E);
  bucket_scatter<<<256, 256, 0, stream>>>(ei, flag, bucketCur, packed, E, chunkE, nbuck);
  bucket_build<<<nbuck, 256, 0, stream>>>(packed, bucketPtr, col, rowptr, invd, N, nbuck);

  const int aggBlocks = (int)(((long)N * 64 + 255) / 256);
  const int gemmBlocks = (N + 127) / 128;   // 782

  agg_kernel<<<aggBlocks, 256, 0, stream>>>(xb, rowptr, col, invd, aggb, maskb, N);
  layer1_kernel<<<gemmBlocks, 256, 0, stream>>>(aggb, xb, w1t, b1, maskb, h1d, N);

  agg_kernel<<<aggBlocks, 256, 0, stream>>>(h1d, rowptr, col, invd, aggb, nullptr, N);
  layer2_kernel<<<gemmBlocks, 256, 0, stream>>>(aggb, h1d, w2t, b2, out, N);
}

// Round 11
// 234.924 us; speedup vs baseline: 1.6498x; 1.0147x over previous
//
#include <hip/hip_runtime.h>
#include <stdint.h>

#define D_FEAT 128
#define D_OUT  64
#define BSH 7              // 128 nodes per bucket
#define MAXB 1024          // max buckets (N <= 131072)

typedef __attribute__((ext_vector_type(8))) short short8;   // 8 bf16 (4 VGPRs)
typedef __attribute__((ext_vector_type(8))) ushort ushort8; // 8 bf16
typedef __attribute__((ext_vector_type(4))) float f32x4;
typedef __attribute__((ext_vector_type(2))) float f32x2;

// ---------------------------------------------------------------------------
// helpers
// ---------------------------------------------------------------------------
__device__ __forceinline__ ushort f2bf(float f) {            // RNE f32->bf16
  uint32_t u = __float_as_uint(f);
  return (ushort)((u + 0x7FFFu + ((u >> 16) & 1u)) >> 16);
}
__device__ __forceinline__ float bf2f(ushort v) {
  return __uint_as_float((uint32_t)v << 16);
}
// accumulate a packed bf16 pair into an f32x2 (one v_pk_add_f32).
// hi half uses as_float(w) directly: 16 low garbage bits < 1 bf16 ULP.
__device__ __forceinline__ void acc2(f32x2& a, uint32_t w) {
  f32x2 t;
  t.x = __uint_as_float(w << 16);
  t.y = __uint_as_float(w);
  a += t;
}

__device__ __forceinline__ void threefry2x32(uint32_t k0, uint32_t k1,
                                             uint32_t& x0, uint32_t& x1) {
  uint32_t k2 = k0 ^ k1 ^ 0x1BD11BDAu;
#define TF_ROT(r) { x0 += x1; x1 = (x1 << (r)) | (x1 >> (32 - (r))); x1 ^= x0; }
  x0 += k0; x1 += k1;
  TF_ROT(13) TF_ROT(15) TF_ROT(26) TF_ROT(6)
  x0 += k1; x1 += k2 + 1u;
  TF_ROT(17) TF_ROT(29) TF_ROT(16) TF_ROT(24)
  x0 += k2; x1 += k0 + 2u;
  TF_ROT(13) TF_ROT(15) TF_ROT(26) TF_ROT(6)
  x0 += k0; x1 += k1 + 3u;
  TF_ROT(17) TF_ROT(29) TF_ROT(16) TF_ROT(24)
  x0 += k1; x1 += k2 + 4u;
  TF_ROT(13) TF_ROT(15) TF_ROT(26) TF_ROT(6)
  x0 += k2; x1 += k0 + 5u;
#undef TF_ROT
}

__device__ __forceinline__ bool keep_bit(uint32_t i) {
  uint32_t t0 = 0u, t1 = i;
  threefry2x32(0u, 42u, t0, t1);
  return (((t0 ^ t1) >> 31) == 0u);
}

// ---------------------------------------------------------------------------
// edge_index dtype detection
// ---------------------------------------------------------------------------
__global__ void detect_kernel(const uint32_t* __restrict__ ei, int* __restrict__ flag) {
  uint32_t v = ei[2 * threadIdx.x + 1];
  unsigned long long nz = __ballot(v != 0u);
  if (threadIdx.x == 0) flag[0] = (nz == 0ull) ? 1 : 0;
}

__device__ __forceinline__ int load_dst(const void* ei, int is64, long E, long e) {
  return is64 ? (int)((const long long*)ei)[E + e] : ((const int*)ei)[E + e];
}
__device__ __forceinline__ int load_src(const void* ei, int is64, long E, long e) {
  return is64 ? (int)((const long long*)ei)[e] : ((const int*)ei)[e];
}

// ---------------------------------------------------------------------------
// input conversions / weight packing
// ---------------------------------------------------------------------------
__global__ __launch_bounds__(256) void convx_kernel(
    const float4* __restrict__ x, ushort* __restrict__ xb, long n4) {
  long i = (long)blockIdx.x * blockDim.x + threadIdx.x;
  if (i >= n4) return;
  float4 v = x[i];
  ushort4 o = {f2bf(v.x), f2bf(v.y), f2bf(v.z), f2bf(v.w)};
  *(ushort4*)(xb + i * 4) = o;
}

// w1t[j][k] = bf16(k<128 ? W1l[k][j] : W1r[k-128][j]),  j<128, k<256
__global__ __launch_bounds__(256) void packw1_kernel(
    const float* __restrict__ Wl, const float* __restrict__ Wr,
    ushort* __restrict__ wt) {
  int idx = blockIdx.x * blockDim.x + threadIdx.x;   // 128*256
  if (idx >= 128 * 256) return;
  int j = idx >> 8, k = idx & 255;
  float v = (k < 128) ? Wl[k * 128 + j] : Wr[(k - 128) * 128 + j];
  wt[j * 256 + k] = f2bf(v);
}

// wt[j][k] = bf16(W[k][j]),  j<64, k<128  (for W2l and W2r separately)
__global__ __launch_bounds__(256) void packw2_kernel(
    const float* __restrict__ W, ushort* __restrict__ wt) {
  int idx = blockIdx.x * blockDim.x + threadIdx.x;   // 64*128
  if (idx >= 64 * 128) return;
  int j = idx >> 7, k = idx & 127;
  wt[j * 128 + k] = f2bf(W[k * 64 + j]);
}

// zero the phantom row N of xb (256 B)
__global__ void zrow_kernel(ushort* __restrict__ b0, int N) {
  if (threadIdx.x < 16)
    *(ushort8*)(b0 + (long)N * D_FEAT + threadIdx.x * 8) = (ushort8){0,0,0,0,0,0,0,0};
}

// ---------------------------------------------------------------------------
// CSR build via bucketed counting sort
// ---------------------------------------------------------------------------
__global__ __launch_bounds__(256) void bucket_hist(
    const void* __restrict__ ei, const int* __restrict__ flag,
    int* __restrict__ bucketCnt, long E, int chunk, int nbuck) {
  __shared__ int cnt[MAXB];
  const int is64 = flag[0];
  long beg = (long)blockIdx.x * chunk;
  long end = beg + chunk; if (end > E) end = E;
  for (int i = threadIdx.x; i < nbuck; i += 256) cnt[i] = 0;
  __syncthreads();
  for (long e = beg + threadIdx.x; e < end; e += 256)
    atomicAdd(&cnt[load_dst(ei, is64, E, e) >> BSH], 1);
  __syncthreads();
  for (int i = threadIdx.x; i < nbuck; i += 256)
    if (cnt[i]) atomicAdd(&bucketCnt[i], cnt[i]);
}

__global__ __launch_bounds__(1024) void bucket_scan(
    const int* __restrict__ bucketCnt, int* __restrict__ bucketPtr,
    int* __restrict__ bucketCur, int* __restrict__ rowptr,
    int N, int nbuck, int E) {
  __shared__ int ts[1024];
  int tid = threadIdx.x;
  int v = (tid < nbuck) ? bucketCnt[tid] : 0;
  ts[tid] = v;
  __syncthreads();
  for (int off = 1; off < 1024; off <<= 1) {
    int t = (tid >= off) ? ts[tid - off] : 0;
    __syncthreads();
    ts[tid] += t;
    __syncthreads();
  }
  if (tid < nbuck) {
    int excl = ts[tid] - v;
    bucketPtr[tid] = excl;
    bucketCur[tid] = excl;
  }
  if (tid == 0) { bucketPtr[nbuck] = E; rowptr[N] = E; }
}

__global__ __launch_bounds__(256) void bucket_scatter(
    const void* __restrict__ ei, const int* __restrict__ flag,
    int* __restrict__ bucketCur, uint32_t* __restrict__ packed,
    long E, int chunk, int nbuck) {
  __shared__ int cnt[MAXB];
  __shared__ int base[MAXB];
  __shared__ int cur[MAXB];
  const int is64 = flag[0];
  long beg = (long)blockIdx.x * chunk;
  long end = beg + chunk; if (end > E) end = E;
  for (int i = threadIdx.x; i < nbuck; i += 256) { cnt[i] = 0; cur[i] = 0; }
  __syncthreads();
  for (long e = beg + threadIdx.x; e < end; e += 256)
    atomicAdd(&cnt[load_dst(ei, is64, E, e) >> BSH], 1);
  __syncthreads();
  for (int i = threadIdx.x; i < nbuck; i += 256)
    base[i] = cnt[i] ? atomicAdd(&bucketCur[i], cnt[i]) : 0;
  __syncthreads();
  for (long e = beg + threadIdx.x; e < end; e += 256) {
    int dst = load_dst(ei, is64, E, e);
    int src = load_src(ei, is64, E, e);
    int b = dst >> BSH;
    int off = atomicAdd(&cur[b], 1);
    packed[base[b] + off] = ((uint32_t)src << BSH) | (uint32_t)(dst & ((1 << BSH) - 1));
  }
}

__global__ __launch_bounds__(256) void bucket_build(
    const uint32_t* __restrict__ packed, const int* __restrict__ bucketPtr,
    int* __restrict__ col, int* __restrict__ rowptr, float* __restrict__ invd,
    int N, int nbuck) {
  __shared__ int lcnt[1 << BSH];
  __shared__ int lbase[1 << BSH];
  __shared__ int lcur[1 << BSH];
  const int b = blockIdx.x;
  const int tid = threadIdx.x;
  const int beg = bucketPtr[b], end = bucketPtr[b + 1];
  if (tid < 128) { lcnt[tid] = 0; lcur[tid] = 0; }
  __syncthreads();
  for (int i = beg + tid; i < end; i += 256)
    atomicAdd(&lcnt[packed[i] & 127], 1);
  __syncthreads();
  if (tid < 128) lbase[tid] = lcnt[tid];
  __syncthreads();
  for (int off = 1; off < 128; off <<= 1) {
    int t = (tid >= off && tid < 128) ? lbase[tid - off] : 0;
    __syncthreads();
    if (tid < 128) lbase[tid] += t;
    __syncthreads();
  }
  if (tid < 128) {
    int excl = lbase[tid] - lcnt[tid];
    lbase[tid] = excl;
    int n = (b << BSH) + tid;
    if (n < N) {
      rowptr[n] = beg + excl;
      int d = lcnt[tid];
      invd[n] = 1.0f / (float)(d > 1 ? d : 1);
    }
  }
  __syncthreads();
  for (int i = beg + tid; i < end; i += 256) {
    uint32_t p = packed[i];
    int l = p & 127;
    int pos = beg + lbase[l] + atomicAdd(&lcur[l], 1);
    col[pos] = (int)(p >> BSH);
  }
}

// ---------------------------------------------------------------------------
// pass-1 mean aggregation over 256 B rows (quarter-wave per row, 16 edges/iter)
// branch-free, zero-row padding; also emits the packed dropout mask
// ---------------------------------------------------------------------------
__global__ __launch_bounds__(256) void agg_kernel(
    const ushort* __restrict__ featb, const int* __restrict__ rowptr,
    const int* __restrict__ col, const float* __restrict__ invd,
    ushort* __restrict__ aggb, unsigned long long* __restrict__ maskb, int N) {
  const int lane = threadIdx.x & 63;
  const int q  = lane >> 4;
  const int sl = lane & 15;
  const uint32_t slb = (uint32_t)sl * 16u;
  int n = (int)(((long)blockIdx.x * blockDim.x + threadIdx.x) >> 6);
  if (n >= N) return;

  if (maskb) {
    uint32_t base = (uint32_t)n * 128u;
    bool k0 = keep_bit(base + (uint32_t)lane);
    bool k1 = keep_bit(base + 64u + (uint32_t)lane);
    unsigned long long w0 = __ballot(k0);
    unsigned long long w1 = __ballot(k1);
    if (lane == 0) {
      maskb[2 * n]     = w0;
      maskb[2 * n + 1] = w1;
    }
  }

  const char* xc = (const char*)featb;
  const int beg = rowptr[n], end = rowptr[n + 1];
  const uint32_t zoff = ((uint32_t)N << 8) + slb;

  f32x2 acc[4];
#pragma unroll
  for (int i = 0; i < 4; i++) acc[i] = (f32x2){0.f, 0.f};

  for (int e = beg + q; e < end; e += 16) {
    int c0 = col[e], c1 = col[e + 4], c2 = col[e + 8], c3 = col[e + 12];
    uint32_t o0 = ((uint32_t)c0 << 8) + slb;
    uint32_t o1 = (e + 4  < end) ? (((uint32_t)c1 << 8) + slb) : zoff;
    uint32_t o2 = (e + 8  < end) ? (((uint32_t)c2 << 8) + slb) : zoff;
    uint32_t o3 = (e + 12 < end) ? (((uint32_t)c3 << 8) + slb) : zoff;
    uint4 a = *(const uint4*)(xc + o0);
    uint4 b = *(const uint4*)(xc + o1);
    uint4 c = *(const uint4*)(xc + o2);
    uint4 d = *(const uint4*)(xc + o3);
    acc2(acc[0], a.x); acc2(acc[1], a.y); acc2(acc[2], a.z); acc2(acc[3], a.w);
    acc2(acc[0], b.x); acc2(acc[1], b.y); acc2(acc[2], b.z); acc2(acc[3], b.w);
    acc2(acc[0], c.x); acc2(acc[1], c.y); acc2(acc[2], c.z); acc2(acc[3], c.w);
    acc2(acc[0], d.x); acc2(acc[1], d.y); acc2(acc[2], d.z); acc2(acc[3], d.w);
  }

#pragma unroll
  for (int i = 0; i < 4; i++) {
    acc[i].x += __shfl_xor(acc[i].x, 16);
    acc[i].y += __shfl_xor(acc[i].y, 16);
    acc[i].x += __shfl_xor(acc[i].x, 32);
    acc[i].y += __shfl_xor(acc[i].y, 32);
  }

  if (q == 0) {
    float sc = invd[n];
    ushort8 o;
#pragma unroll
    for (int i = 0; i < 4; i++) {
      o[2 * i]     = f2bf(acc[i].x * sc);
      o[2 * i + 1] = f2bf(acc[i].y * sc);
    }
    *(ushort8*)(aggb + (long)n * D_FEAT + sl * 8) = o;
  }
}

// ---------------------------------------------------------------------------
// pass-2 mean aggregation over 128 B rows (eighth-wave per row, 16 edges/iter)
// gathers the PRE-TRANSFORMED y2 = h1@W2l (linearity: mean(h1[src])@W2l ==
// mean(y2[src])) -- half the bytes & unpack VALU of a 256 B gather
// ---------------------------------------------------------------------------
__global__ __launch_bounds__(256) void agg64_kernel(
    const ushort* __restrict__ featb, const int* __restrict__ rowptr,
    const int* __restrict__ col, const float* __restrict__ invd,
    ushort* __restrict__ aggo, int N) {
  const int lane = threadIdx.x & 63;
  const int g  = lane >> 3;            // oct 0..7: which edge of the group
  const int sl = lane & 7;             // 16 B slice of the 128 B row
  const uint32_t slb = (uint32_t)sl * 16u;
  int n = (int)(((long)blockIdx.x * blockDim.x + threadIdx.x) >> 6);
  if (n >= N) return;

  const char* xc = (const char*)featb;
  const int beg = rowptr[n], end = rowptr[n + 1];
  const uint32_t zoff = ((uint32_t)N << 7) + slb;

  f32x2 acc[4];
#pragma unroll
  for (int i = 0; i < 4; i++) acc[i] = (f32x2){0.f, 0.f};

  for (int e = beg + g; e < end; e += 16) {
    int c0 = col[e], c1 = col[e + 8];
    uint32_t o0 = ((uint32_t)c0 << 7) + slb;
    uint32_t o1 = (e + 8 < end) ? (((uint32_t)c1 << 7) + slb) : zoff;
    uint4 a = *(const uint4*)(xc + o0);
    uint4 b = *(const uint4*)(xc + o1);
    acc2(acc[0], a.x); acc2(acc[1], a.y); acc2(acc[2], a.z); acc2(acc[3], a.w);
    acc2(acc[0], b.x); acc2(acc[1], b.y); acc2(acc[2], b.z); acc2(acc[3], b.w);
  }

  // combine the 8 oct partial sums (lanes with equal sl)
#pragma unroll
  for (int i = 0; i < 4; i++) {
    acc[i].x += __shfl_xor(acc[i].x, 8);
    acc[i].y += __shfl_xor(acc[i].y, 8);
    acc[i].x += __shfl_xor(acc[i].x, 16);
    acc[i].y += __shfl_xor(acc[i].y, 16);
    acc[i].x += __shfl_xor(acc[i].x, 32);
    acc[i].y += __shfl_xor(acc[i].y, 32);
  }

  if (g == 0) {
    float sc = invd[n];
    ushort8 o;
#pragma unroll
    for (int i = 0; i < 4; i++) {
      o[2 * i]     = f2bf(acc[i].x * sc);
      o[2 * i + 1] = f2bf(acc[i].y * sc);
    }
    *(ushort8*)(aggo + (long)n * D_OUT + sl * 8) = o;
  }
}

// ---------------------------------------------------------------------------
// layer 1 (MFMA, LDS-staged weights): h1d = bf16(dropout(relu([agg|x]@W1+b1)))
// ---------------------------------------------------------------------------
__global__ __launch_bounds__(256) void layer1_kernel(
    const ushort* __restrict__ aggb, const ushort* __restrict__ xb,
    const ushort* __restrict__ w1t, const float* __restrict__ b1,
    const unsigned long long* __restrict__ maskb,
    ushort* __restrict__ h1d, int N) {
  __shared__ ushort w1s[128 * 256];   // 64 KB
  const int tid = threadIdx.x;
  const int lane = tid & 63;
  const int wv = tid >> 6;
  const int r16 = lane & 15;
  const int kg = lane >> 4;

  {
    const uint32_t swz = ((uint32_t)(tid >> 5) & 7u) << 4;
#pragma unroll
    for (int i = 0; i < 16; i++) {
      uint32_t byte = (uint32_t)i * 4096u + (uint32_t)tid * 16u;
      uint4 v = *(const uint4*)((const char*)w1t + byte);
      *(uint4*)((char*)w1s + (byte ^ swz)) = v;
    }
  }
  __syncthreads();

  const int node_base = blockIdx.x * 128 + wv * 32;
  int ar0 = node_base + r16;       if (ar0 >= N) ar0 = N - 1;
  int ar1 = node_base + 16 + r16;  if (ar1 >= N) ar1 = N - 1;

  f32x4 acc0[8], acc1[8];
#pragma unroll
  for (int i = 0; i < 8; i++) {
    acc0[i] = (f32x4){0.f, 0.f, 0.f, 0.f};
    acc1[i] = (f32x4){0.f, 0.f, 0.f, 0.f};
  }

  const ushort* a0g = aggb + (long)ar0 * 128 + kg * 8;
  const ushort* a0x = xb   + (long)ar0 * 128 + kg * 8;
  const ushort* a1g = aggb + (long)ar1 * 128 + kg * 8;
  const ushort* a1x = xb   + (long)ar1 * 128 + kg * 8;
  const uint32_t rswz = ((uint32_t)(r16 & 7)) << 4;

#pragma unroll
  for (int s = 0; s < 8; s++) {
    short8 aT0 = (s < 4) ? *(const short8*)(a0g + s * 32)
                         : *(const short8*)(a0x + (s - 4) * 32);
    short8 aT1 = (s < 4) ? *(const short8*)(a1g + s * 32)
                         : *(const short8*)(a1x + (s - 4) * 32);
#pragma unroll
    for (int ct = 0; ct < 8; ct++) {
      uint32_t boff = ((uint32_t)(ct * 16 + r16) * 512u +
                       (uint32_t)s * 64u + (uint32_t)kg * 16u) ^ rswz;
      short8 b = *(const short8*)((const char*)w1s + boff);
      acc0[ct] = __builtin_amdgcn_mfma_f32_16x16x32_bf16(aT0, b, acc0[ct], 0, 0, 0);
      acc1[ct] = __builtin_amdgcn_mfma_f32_16x16x32_bf16(aT1, b, acc1[ct], 0, 0, 0);
    }
  }

  float bbv[8];
#pragma unroll
  for (int ct = 0; ct < 8; ct++) bbv[ct] = b1[ct * 16 + r16];

#pragma unroll
  for (int t = 0; t < 2; t++) {
    const f32x4* acc = t ? acc1 : acc0;
    int nb = node_base + t * 16;
#pragma unroll
    for (int r = 0; r < 4; r++) {
      int n = nb + kg * 4 + r;
      if (n < N) {
        unsigned long long m0 = maskb[2 * n];
        unsigned long long m1 = maskb[2 * n + 1];
#pragma unroll
        for (int ct = 0; ct < 8; ct++) {
          int j = ct * 16 + r16;
          float h = fmaxf(acc[ct][r] + bbv[ct], 0.f);
          unsigned long long w = (j & 64) ? m1 : m0;
          bool keep = (w >> (j & 63)) & 1ull;
          h1d[(long)n * 128 + j] = keep ? f2bf(2.0f * h) : (ushort)0;
        }
      }
    }
  }
}

// ---------------------------------------------------------------------------
// layer 2a (MFMA, LDS-staged): y2 = bf16(h1 @ W2l)   [K=128, N x 64]
// block 0 also zeroes y2's phantom row N.
// ---------------------------------------------------------------------------
__global__ __launch_bounds__(256) void layer2a_kernel(
    const ushort* __restrict__ h1d, const ushort* __restrict__ w2lt,
    ushort* __restrict__ y2, int N) {
  __shared__ ushort ws[64 * 128];     // 16 KB
  const int tid = threadIdx.x;
  const int lane = tid & 63;
  const int wv = tid >> 6;
  const int r16 = lane & 15;
  const int kg = lane >> 4;

  {
    const uint32_t swz = ((uint32_t)(tid >> 4) & 7u) << 4;
#pragma unroll
    for (int i = 0; i < 4; i++) {
      uint32_t byte = (uint32_t)i * 4096u + (uint32_t)tid * 16u;
      uint4 v = *(const uint4*)((const char*)w2lt + byte);
      *(uint4*)((char*)ws + (byte ^ swz)) = v;
    }
  }
  if (blockIdx.x == 0 && tid < 8)
    *(ushort8*)(y2 + (long)N * D_OUT + tid * 8) = (ushort8){0,0,0,0,0,0,0,0};
  __syncthreads();

  const int node_base = blockIdx.x * 128 + wv * 32;
  int ar0 = node_base + r16;       if (ar0 >= N) ar0 = N - 1;
  int ar1 = node_base + 16 + r16;  if (ar1 >= N) ar1 = N - 1;

  f32x4 acc0[4], acc1[4];
#pragma unroll
  for (int i = 0; i < 4; i++) {
    acc0[i] = (f32x4){0.f, 0.f, 0.f, 0.f};
    acc1[i] = (f32x4){0.f, 0.f, 0.f, 0.f};
  }

  const ushort* a0 = h1d + (long)ar0 * 128 + kg * 8;
  const ushort* a1 = h1d + (long)ar1 * 128 + kg * 8;
  const uint32_t rswz = ((uint32_t)(r16 & 7)) << 4;

#pragma unroll
  for (int s = 0; s < 4; s++) {
    short8 aT0 = *(const short8*)(a0 + s * 32);
    short8 aT1 = *(const short8*)(a1 + s * 32);
#pragma unroll
    for (int ct = 0; ct < 4; ct++) {
      uint32_t boff = ((uint32_t)(ct * 16 + r16) * 256u +
                       (uint32_t)s * 64u + (uint32_t)kg * 16u) ^ rswz;
      short8 b = *(const short8*)((const char*)ws + boff);
      acc0[ct] = __builtin_amdgcn_mfma_f32_16x16x32_bf16(aT0, b, acc0[ct], 0, 0, 0);
      acc1[ct] = __builtin_amdgcn_mfma_f32_16x16x32_bf16(aT1, b, acc1[ct], 0, 0, 0);
    }
  }

#pragma unroll
  for (int t = 0; t < 2; t++) {
    const f32x4* acc = t ? acc1 : acc0;
    int nb = node_base + t * 16;
#pragma unroll
    for (int r = 0; r < 4; r++) {
      int n = nb + kg * 4 + r;
      if (n < N) {
#pragma unroll
        for (int ct = 0; ct < 4; ct++)
          y2[(long)n * D_OUT + ct * 16 + r16] = f2bf(acc[ct][r]);
      }
    }
  }
}

// ---------------------------------------------------------------------------
// layer 2b (MFMA, LDS-staged) + log_softmax:
// out = logsm(aggy + h1@W2r + b2)   [K=128]
// ---------------------------------------------------------------------------
__global__ __launch_bounds__(256) void layer2b_kernel(
    const ushort* __restrict__ h1d, const ushort* __restrict__ aggy,
    const ushort* __restrict__ w2rt, const float* __restrict__ b2,
    float* __restrict__ out, int N) {
  __shared__ ushort ws[64 * 128];     // 16 KB
  const int tid = threadIdx.x;
  const int lane = tid & 63;
  const int wv = tid >> 6;
  const int r16 = lane & 15;
  const int kg = lane >> 4;

  {
    const uint32_t swz = ((uint32_t)(tid >> 4) & 7u) << 4;
#pragma unroll
    for (int i = 0; i < 4; i++) {
      uint32_t byte = (uint32_t)i * 4096u + (uint32_t)tid * 16u;
      uint4 v = *(const uint4*)((const char*)w2rt + byte);
      *(uint4*)((char*)ws + (byte ^ swz)) = v;
    }
  }
  __syncthreads();

  const int node_base = blockIdx.x * 128 + wv * 32;
  int ar0 = node_base + r16;       if (ar0 >= N) ar0 = N - 1;
  int ar1 = node_base + 16 + r16;  if (ar1 >= N) ar1 = N - 1;

  f32x4 acc0[4], acc1[4];
#pragma unroll
  for (int i = 0; i < 4; i++) {
    acc0[i] = (f32x4){0.f, 0.f, 0.f, 0.f};
    acc1[i] = (f32x4){0.f, 0.f, 0.f, 0.f};
  }

  const ushort* a0 = h1d + (long)ar0 * 128 + kg * 8;
  const ushort* a1 = h1d + (long)ar1 * 128 + kg * 8;
  const uint32_t rswz = ((uint32_t)(r16 & 7)) << 4;

#pragma unroll
  for (int s = 0; s < 4; s++) {
    short8 aT0 = *(const short8*)(a0 + s * 32);
    short8 aT1 = *(const short8*)(a1 + s * 32);
#pragma unroll
    for (int ct = 0; ct < 4; ct++) {
      uint32_t boff = ((uint32_t)(ct * 16 + r16) * 256u +
                       (uint32_t)s * 64u + (uint32_t)kg * 16u) ^ rswz;
      short8 b = *(const short8*)((const char*)ws + boff);
      acc0[ct] = __builtin_amdgcn_mfma_f32_16x16x32_bf16(aT0, b, acc0[ct], 0, 0, 0);
      acc1[ct] = __builtin_amdgcn_mfma_f32_16x16x32_bf16(aT1, b, acc1[ct], 0, 0, 0);
    }
  }

  float bb[4];
#pragma unroll
  for (int ct = 0; ct < 4; ct++) bb[ct] = b2[ct * 16 + r16];

#pragma unroll
  for (int t = 0; t < 2; t++) {
    const f32x4* acc = t ? acc1 : acc0;
    int nb = node_base + t * 16;
#pragma unroll
    for (int r = 0; r < 4; r++) {
      int n = nb + kg * 4 + r;
      int gn = (n < N) ? n : (N - 1);
      float v[4];
#pragma unroll
      for (int ct = 0; ct < 4; ct++)
        v[ct] = acc[ct][r] + bb[ct] + bf2f(aggy[(long)gn * D_OUT + ct * 16 + r16]);
      float m = fmaxf(fmaxf(v[0], v[1]), fmaxf(v[2], v[3]));
#pragma unroll
      for (int off = 1; off < 16; off <<= 1) m = fmaxf(m, __shfl_xor(m, off));
      float s = expf(v[0] - m) + expf(v[1] - m) + expf(v[2] - m) + expf(v[3] - m);
#pragma unroll
      for (int off = 1; off < 16; off <<= 1) s += __shfl_xor(s, off);
      float ls = logf(s);
      if (n < N) {
#pragma unroll
        for (int ct = 0; ct < 4; ct++)
          out[(long)n * 64 + ct * 16 + r16] = v[ct] - m - ls;
      }
    }
  }
}

// ---------------------------------------------------------------------------
extern "C" void kernel_launch(void* const* d_in, const int* in_sizes, int n_in,
                              void* d_out, int out_size, void* d_ws, size_t ws_size,
                              hipStream_t stream) {
  const float* x   = (const float*)d_in[0];
  const void*  ei  = d_in[1];
  const float* W1l = (const float*)d_in[2];
  const float* b1  = (const float*)d_in[3];
  const float* W1r = (const float*)d_in[4];
  const float* W2l = (const float*)d_in[5];
  const float* b2  = (const float*)d_in[6];
  const float* W2r = (const float*)d_in[7];
  float* out = (float*)d_out;

  const int  N  = in_sizes[0] / D_FEAT;    // 100000
  const long E  = (long)in_sizes[1] / 2;   // 1600000
  const long NF = (long)N * D_FEAT;        // 12.8M
  const int  nbuck = (N + (1 << BSH) - 1) >> BSH;   // 782

  char* ws = (char*)d_ws;
  size_t off = 0;
  auto alloc = [&](size_t bytes) -> void* {
    void* p = ws + off;
    off = (off + bytes + 255) & ~(size_t)255;
    return p;
  };
  int*      bucketCnt = (int*)alloc(sizeof(int) * MAXB);
  int*      bucketPtr = (int*)alloc(sizeof(int) * (MAXB + 1));
  int*      bucketCur = (int*)alloc(sizeof(int) * MAXB);
  int*      rowptr    = (int*)alloc(sizeof(int) * (N + 1));
  int*      col       = (int*)alloc(sizeof(int) * (E + 16));      // +16 slack
  uint32_t* packed    = (uint32_t*)alloc(sizeof(uint32_t) * E);
  float*    invd      = (float*)alloc(sizeof(float) * N);
  ushort*   xb        = (ushort*)alloc(sizeof(ushort) * (NF + D_FEAT));  // +zero row
  ushort*   aggb      = (ushort*)alloc(sizeof(ushort) * (NF + 256));     // reused: y2+aggy
  ushort*   h1d       = (ushort*)alloc(sizeof(ushort) * NF);
  ushort*   w1t       = (ushort*)alloc(sizeof(ushort) * 128 * 256);
  ushort*   w2lt      = (ushort*)alloc(sizeof(ushort) * 64 * 128);
  ushort*   w2rt      = (ushort*)alloc(sizeof(ushort) * 64 * 128);
  unsigned long long* maskb = (unsigned long long*)alloc(sizeof(unsigned long long) * 2 * N);
  int*      flag      = (int*)alloc(sizeof(int));

  // aggb region reused after layer1 consumes it:
  ushort* y2   = aggb;                              // N x 64 (+zero row N)
  ushort* aggy = aggb + ((size_t)NF / 2 + 128);     // N x 64

  const int NBLK = 512;
  const int chunkE = (int)((E + NBLK - 1) / NBLK);

  hipMemsetAsync(bucketCnt, 0, sizeof(int) * MAXB, stream);

  detect_kernel<<<1, 64, 0, stream>>>((const uint32_t*)ei, flag);
  convx_kernel<<<(int)((NF / 4 + 255) / 256), 256, 0, stream>>>((const float4*)x, xb, NF / 4);
  zrow_kernel<<<1, 16, 0, stream>>>(xb, N);
  packw1_kernel<<<128, 256, 0, stream>>>(W1l, W1r, w1t);
  packw2_kernel<<<32, 256, 0, stream>>>(W2l, w2lt);
  packw2_kernel<<<32, 256, 0, stream>>>(W2r, w2rt);

  bucket_hist<<<NBLK, 256, 0, stream>>>(ei, flag, bucketCnt, E, chunkE, nbuck);
  bucket_scan<<<1, 1024, 0, stream>>>(bucketCnt, bucketPtr, bucketCur, rowptr, N, nbuck, (int)E);
  bucket_scatter<<<NBLK, 256, 0, stream>>>(ei, flag, bucketCur, packed, E, chunkE, nbuck);
  bucket_build<<<nbuck, 256, 0, stream>>>(packed, bucketPtr, col, rowptr, invd, N, nbuck);

  const int aggBlocks = (int)(((long)N * 64 + 255) / 256);
  const int gemmBlocks = (N + 127) / 128;   // 782

  agg_kernel<<<aggBlocks, 256, 0, stream>>>(xb, rowptr, col, invd, aggb, maskb, N);
  layer1_kernel<<<gemmBlocks, 256, 0, stream>>>(aggb, xb, w1t, b1, maskb, h1d, N);

  layer2a_kernel<<<gemmBlocks, 256, 0, stream>>>(h1d, w2lt, y2, N);
  agg64_kernel<<<aggBlocks, 256, 0, stream>>>(y2, rowptr, col, invd, aggy, N);
  layer2b_kernel<<<gemmBlocks, 256, 0, stream>>>(h1d, aggy, w2rt, b2, out, N);
}